// Round 13
// baseline (100.566 us; speedup 1.0000x reference)
//
#include <hip/hip_runtime.h>

typedef __attribute__((ext_vector_type(8))) __bf16 bf16x8;
typedef __attribute__((ext_vector_type(4))) __bf16 bf16x4;
typedef __attribute__((ext_vector_type(4))) float  f32x4;

// Problem: x (8,512,32,32) fp32 -> B=8, C=512, T=1024; 32 groups; 8 heads (ch=64)

// ws layout (bytes)
static constexpr size_t QKV_OFF = 0;                     // fp32 (8,1536,1024) 48MB
static constexpr size_t HT_OFF  = 50331648;              // bf16 (8,1024,512) 8MB: hT then aT
static constexpr size_t WQ_OFF  = HT_OFF + 8388608;      // bf16 (1536,512)
static constexpr size_t WP_OFF  = WQ_OFF + 1572864;      // bf16 (512,512)
static constexpr size_t MM_OFF  = WP_OFF + 524288;       // pmm partials (6144B) + gn stats (2048B)
static constexpr size_t GST_OFF = MM_OFF + 6144;         // mean[256], rstd[256] f32
static constexpr size_t KI_OFF  = MM_OFF + 8192;         // bf16 (64,1024,64) 8MB
static constexpr size_t VI_OFF  = KI_OFF + 8388608;      // bf16 (64,64,1024) 8MB
static constexpr size_t NEED_NEW = VI_OFF + 8388608;

// integer-valued dequant core: clip(rint(x/s)+zp,0,255)-zp == clip(rint(x/s), -zp, 255-zp)
__device__ __forceinline__ float dqi(float x, float inv_s, float zp) {
    float y = rintf(x * inv_s);
    return fminf(fmaxf(y, -zp), 255.0f - zp);
}
__device__ __forceinline__ f32x4 mfma16(bf16x8 a, bf16x8 b, f32x4 c) {
    return __builtin_amdgcn_mfma_f32_16x16x32_bf16(a, b, c, 0, 0, 0);
}
__device__ __forceinline__ float exp2i(float x) {  // raw v_exp_f32 (2^x)
    float r;
    asm("v_exp_f32 %0, %1" : "=v"(r) : "v"(x));
    return r;
}
__device__ __forceinline__ void glds16(const __bf16* g, __bf16* l) {
    __builtin_amdgcn_global_load_lds((const __attribute__((address_space(1))) void*)g,
                                     (__attribute__((address_space(3))) void*)l, 16, 0, 0);
}
template <int N> __device__ __forceinline__ void waitv() {
    asm volatile("s_waitcnt vmcnt(%0)" :: "n"(N) : "memory");
}
__device__ __forceinline__ void bar_raw() {
    asm volatile("s_barrier" ::: "memory");
}
__device__ __forceinline__ unsigned pk2(float a, float b) {  // bf16x2 pack (a=low)
    union { __bf16 h; unsigned short u; } ua, ub;
    ua.h = (__bf16)a; ub.h = (__bf16)b;
    return ((unsigned)ub.u << 16) | (unsigned)ua.u;
}

// reduce pmm[id][256][2] partials -> (mn, mx). 256-thread version.
__device__ __forceinline__ void red_mm(const float* __restrict__ pmm, int id, int tid,
                                       float* sred, float& mn_out, float& mx_out) {
    float mn = pmm[id * 512 + tid * 2];
    float mx = pmm[id * 512 + tid * 2 + 1];
#pragma unroll
    for (int m = 1; m < 64; m <<= 1) {
        mn = fminf(mn, __shfl_xor(mn, m));
        mx = fmaxf(mx, __shfl_xor(mx, m));
    }
    if ((tid & 63) == 0) { sred[(tid >> 6) * 2] = mn; sred[(tid >> 6) * 2 + 1] = mx; }
    __syncthreads();
    mn = fminf(fminf(sred[0], sred[2]), fminf(sred[4], sred[6]));
    mx = fmaxf(fmaxf(sred[1], sred[3]), fmaxf(sred[5], sred[7]));
    __syncthreads();
    mn_out = fminf(mn, 0.0f);
    mx_out = fmaxf(mx, 0.0f);
}

// 512-thread version (slots read twice; harmless for min/max)
__device__ __forceinline__ void red_mm8(const float* __restrict__ pmm, int id, int tid,
                                        float* sred, float& mn_out, float& mx_out) {
    int slot = tid & 255;
    float mn = pmm[id * 512 + slot * 2];
    float mx = pmm[id * 512 + slot * 2 + 1];
#pragma unroll
    for (int m = 1; m < 64; m <<= 1) {
        mn = fminf(mn, __shfl_xor(mn, m));
        mx = fmaxf(mx, __shfl_xor(mx, m));
    }
    if ((tid & 63) == 0) { sred[(tid >> 6) * 2] = mn; sred[(tid >> 6) * 2 + 1] = mx; }
    __syncthreads();
    float a = fminf(fminf(sred[0], sred[2]), fminf(sred[4], sred[6]));
    float b = fminf(fminf(sred[8], sred[10]), fminf(sred[12], sred[14]));
    mn = fminf(a, b);
    a = fmaxf(fmaxf(sred[1], sred[3]), fmaxf(sred[5], sred[7]));
    b = fmaxf(fmaxf(sred[9], sred[11]), fmaxf(sred[13], sred[15]));
    mx = fmaxf(a, b);
    __syncthreads();
    mn_out = fminf(mn, 0.0f);
    mx_out = fmaxf(mx, 0.0f);
}

// ---------------- gnstats: weight fp32->bf16 convert + per-(b,g) mean/rstd ----------------
__global__ __launch_bounds__(256) void gnstats(const float* __restrict__ x,
                                               const float* __restrict__ qw,
                                               __bf16* __restrict__ wq,
                                               const float* __restrict__ pw,
                                               __bf16* __restrict__ wp,
                                               float* __restrict__ gst) {
    int bid = blockIdx.x, tid = threadIdx.x;
    if (bid < 1024) {
        if (bid < 768) {
            int i = bid * 256 + tid;
            float4 v = ((const float4*)qw)[i];
            bf16x4 o = {(__bf16)v.x, (__bf16)v.y, (__bf16)v.z, (__bf16)v.w};
            ((bf16x4*)wq)[i] = o;
        } else {
            int i = (bid - 768) * 256 + tid;
            float4 v = ((const float4*)pw)[i];
            bf16x4 o = {(__bf16)v.x, (__bf16)v.y, (__bf16)v.z, (__bf16)v.w};
            ((bf16x4*)wp)[i] = o;
        }
        return;
    }
    int blk = bid - 1024;
    int b = blk >> 5, g = blk & 31;
    const float* xp = x + (size_t)(b * 512 + g * 16) * 1024;

    float sum = 0.f, ss = 0.f;
#pragma unroll
    for (int i = 0; i < 16; ++i) {
        float4 v = *(const float4*)(xp + (size_t)i * 1024 + tid * 4);
        sum += v.x + v.y + v.z + v.w;
        ss  += v.x * v.x + v.y * v.y + v.z * v.z + v.w * v.w;
    }
#pragma unroll
    for (int m = 1; m < 64; m <<= 1) {
        sum += __shfl_xor(sum, m);
        ss  += __shfl_xor(ss, m);
    }
    __shared__ float s1[4], s2[4];
    int wid = tid >> 6;
    if ((tid & 63) == 0) { s1[wid] = sum; s2[wid] = ss; }
    __syncthreads();
    if (tid == 0) {
        sum = s1[0] + s1[1] + s1[2] + s1[3];
        ss  = s2[0] + s2[1] + s2[2] + s2[3];
        float mean = sum * (1.0f / 16384.0f);
        float var  = ss * (1.0f / 16384.0f) - mean * mean;
        gst[blk]       = mean;
        gst[256 + blk] = rsqrtf(var + 1e-5f);
    }
}

// ---------------- gnapply: t-major normalize + transpose, coalesced both sides ----------------
__global__ __launch_bounds__(256) void gnapply(const float* __restrict__ x,
                                               const float* __restrict__ w,
                                               const float* __restrict__ bv,
                                               const float* __restrict__ gst,
                                               __bf16* __restrict__ hT) {
    int f = blockIdx.x;
    int b = f & 7, ts = f >> 3;
    int t0 = ts * 32;
    int tid = threadIdx.x;

    __shared__ __bf16 sH[32][520];
    int cl = tid >> 3;
    int tl = (tid & 7) * 4;

#pragma unroll
    for (int ci = 0; ci < 16; ++ci) {
        int c = ci * 32 + cl;
        int g = c >> 4;
        float mean = gst[b * 32 + g];
        float rstd = gst[256 + b * 32 + g];
        float wc = w[c] * rstd, bc = bv[c];
        float4 v = *(const float4*)(x + ((size_t)(b * 512 + c)) * 1024 + t0 + tl);
        sH[tl + 0][c] = (__bf16)((v.x - mean) * wc + bc);
        sH[tl + 1][c] = (__bf16)((v.y - mean) * wc + bc);
        sH[tl + 2][c] = (__bf16)((v.z - mean) * wc + bc);
        sH[tl + 3][c] = (__bf16)((v.w - mean) * wc + bc);
    }
    __syncthreads();
    int lane = tid & 63, wv = tid >> 6;
#pragma unroll
    for (int it = 0; it < 8; ++it) {
        int row = it * 4 + wv;
        bf16x8 o = *(const bf16x8*)&sH[row][lane * 8];
        *(bf16x8*)(hT + ((size_t)(b * 1024 + t0 + row)) * 512 + lane * 8) = o;
    }
}

// ---------------- MFMA GEMM v5: BK=64 conflict-free swizzle + counted-vmcnt dbuf, NO atomics ----------------
template <int MTILE, int MOT, bool MINMAX, bool RESID>
__global__ __launch_bounds__(256, 2) void mgemm5(const __bf16* __restrict__ A,   // [M][512]
                                                 const __bf16* __restrict__ Bt,  // [8][1024][512]
                                                 const float* __restrict__ bias,
                                                 const float* __restrict__ resid,
                                                 float* __restrict__ out,
                                                 int M, float* __restrict__ pmm) {
    constexpr int NF  = (MTILE == 128) ? 4 : 2;
    constexpr int ASZ = MTILE * 64;
    constexpr int BSZ = 128 * 64;
    constexpr int LA  = MTILE / 32;
    constexpr int L   = LA + 4;
    constexpr int STG = 2 * (ASZ + BSZ) * 2;
    constexpr int CSB = 64 * 132 * 4;
    __shared__ __attribute__((aligned(16))) char smem_raw[(STG > CSB) ? STG : CSB];
    __bf16* sA0 = (__bf16*)smem_raw;
    __bf16* sA1 = sA0 + ASZ;
    __bf16* sB0 = sA1 + ASZ;
    __bf16* sB1 = sB0 + BSZ;
    __shared__ float smn[4], smx[4];

    int tid = threadIdx.x;
    int l = tid & 63, w = tid >> 6;
    int lo = l & 15, hi = l >> 4;

    int f = blockIdx.x;
    constexpr int NWG = MOT * 64;
    int wg = (f & 7) * (NWG / 8) + (f >> 3);
    int mo = wg % MOT, nb = wg / MOT;
    int nt = nb & 7, b = nb >> 3;

    const __bf16* Ap = A + (size_t)mo * MTILE * 512;
    const __bf16* Bp = Bt + ((size_t)b * 1024 + (size_t)nt * 128) * 512;
    int m0 = (MTILE == 128) ? (w >> 1) * 64 : 0;
    int n0 = (MTILE == 128) ? (w & 1) * 64 : w * 32;
    f32x4 acc[4][NF] = {};
    int scd = tid & 7;

    auto STAGE = [&](__bf16* dA, __bf16* dB, int k0) {
#pragma unroll
        for (int p = 0; p < LA; ++p) {
            int lin = p * 2048 + tid * 8;
            int row = lin >> 6;
            glds16(Ap + (size_t)row * 512 + k0 + ((scd ^ (row & 7)) << 3), dA + lin);
        }
#pragma unroll
        for (int p = 0; p < 4; ++p) {
            int lin = p * 2048 + tid * 8;
            int row = lin >> 6;
            glds16(Bp + (size_t)row * 512 + k0 + ((scd ^ (row & 7)) << 3), dB + lin);
        }
    };
    auto COMPUTE = [&](const __bf16* cA, const __bf16* cB) {
#pragma unroll
        for (int kk = 0; kk < 2; ++kk) {
            int rch = ((kk * 4 + hi) ^ (lo & 7)) << 3;
            bf16x8 af[4], bfr[NF];
#pragma unroll
            for (int i = 0; i < 4; ++i) af[i] = *(const bf16x8*)&cA[(m0 + 16 * i + lo) * 64 + rch];
#pragma unroll
            for (int j = 0; j < NF; ++j) bfr[j] = *(const bf16x8*)&cB[(n0 + 16 * j + lo) * 64 + rch];
#pragma unroll
            for (int i = 0; i < 4; ++i)
#pragma unroll
                for (int j = 0; j < NF; ++j) acc[i][j] = mfma16(af[i], bfr[j], acc[i][j]);
        }
    };

    STAGE(sA0, sB0, 0);
#pragma unroll
    for (int kp = 0; kp < 8; kp += 2) {
        if (kp + 1 < 8) { STAGE(sA1, sB1, (kp + 1) * 64); waitv<L>(); } else { waitv<0>(); }
        bar_raw();
        COMPUTE(sA0, sB0);
        bar_raw();
        if (kp + 2 < 8) { STAGE(sA0, sB0, (kp + 2) * 64); waitv<L>(); } else { waitv<0>(); }
        bar_raw();
        COMPUTE(sA1, sB1);
        bar_raw();
    }

    float* cs = (float*)smem_raw;
    float mn = 1e30f, mx = -1e30f;
    constexpr int NH = (MTILE == 128) ? 2 : 1;
#pragma unroll
    for (int h = 0; h < NH; ++h) {
        __syncthreads();
        if (MTILE == 64 || (w >> 1) == h) {
#pragma unroll
            for (int i = 0; i < 4; ++i)
#pragma unroll
                for (int r = 0; r < 4; ++r) {
                    int rl = 16 * i + hi * 4 + r;
                    float bi = bias[mo * MTILE + h * 64 + rl];
#pragma unroll
                    for (int j = 0; j < NF; ++j)
                        cs[rl * 132 + n0 + 16 * j + lo] = acc[i][j][r] + bi;
                }
        }
        __syncthreads();
#pragma unroll
        for (int it = 0; it < 8; ++it) {
            int lin = it * 256 + tid;
            int rr = lin >> 5, cc = (lin & 31) << 2;
            float4 v = *(const float4*)&cs[rr * 132 + cc];
            if (MINMAX) {
                mn = fminf(mn, fminf(fminf(v.x, v.y), fminf(v.z, v.w)));
                mx = fmaxf(mx, fmaxf(fmaxf(v.x, v.y), fmaxf(v.z, v.w)));
            }
            int grow = mo * MTILE + h * 64 + rr;
            size_t gaddr = ((size_t)b * M + grow) * 1024 + nt * 128 + cc;
            if (RESID) {
                float4 rv = *(const float4*)&resid[gaddr];
                v.x += rv.x; v.y += rv.y; v.z += rv.z; v.w += rv.w;
            }
            *(float4*)&out[gaddr] = v;
        }
    }

    if (MINMAX) {
#pragma unroll
        for (int msk = 1; msk < 64; msk <<= 1) {
            mn = fminf(mn, __shfl_xor(mn, msk));
            mx = fmaxf(mx, __shfl_xor(mx, msk));
        }
        if (l == 0) { smn[w] = mn; smx[w] = mx; }
        __syncthreads();
        if (tid == 0) {
            mn = fminf(fminf(smn[0], smn[1]), fminf(smn[2], smn[3]));
            mx = fmaxf(fmaxf(smx[0], smx[1]), fmaxf(smx[2], smx[3]));
            int id = mo >> 2;
            int slot = nb * 4 + (mo & 3);
            pmm[id * 512 + slot * 2]     = mn;
            pmm[id * 512 + slot * 2 + 1] = mx;
        }
    }
}

// ---------------- quant K/V pass, XCD-aligned: batch b on XCD b ----------------
__global__ __launch_bounds__(256) void quant_kv(const float* __restrict__ qkv,
                                                const float* __restrict__ pmm,
                                                __bf16* __restrict__ ki,
                                                __bf16* __restrict__ vi) {
    int f = blockIdx.x;
    int b = f & 7;
    int r2 = f >> 3;
    int hh = r2 & 7, tt = r2 >> 3;
    int bh = b * 8 + hh;
    int t0 = tt * 64;
    const float* kg = qkv + ((size_t)(b * 1536 + hh * 192) + 64) * 1024;
    const float* vg = kg + 65536;
    int tid = threadIdx.x;

    __shared__ float sred[8];
    float mn1, mx1, mn2, mx2;
    red_mm(pmm, 1, tid, sred, mn1, mx1);
    red_mm(pmm, 2, tid, sred, mn2, mx2);
    float ksc = fmaxf((mx1 - mn1) * (1.f / 255.f), 1e-8f), kzp = rintf(-mn1 / ksc);
    float vsc = fmaxf((mx2 - mn2) * (1.f / 255.f), 1e-8f), vzp = rintf(-mn2 / vsc);
    float inv_k = 1.f / ksc, inv_v = 1.f / vsc;

    __shared__ __bf16 sT[64][68];
    int cr = tid >> 4, t4 = tid & 15;
    int s = tid >> 2, c0 = (tid & 3) * 16;

    __bf16* vd = vi + (size_t)bh * 65536;
#pragma unroll
    for (int r = 0; r < 4; ++r) {
        int c = 16 * r + cr;
        float4 v = *(const float4*)(vg + (size_t)c * 1024 + t0 + t4 * 4);
        bf16x4 o = {(__bf16)dqi(v.x, inv_v, vzp), (__bf16)dqi(v.y, inv_v, vzp),
                    (__bf16)dqi(v.z, inv_v, vzp), (__bf16)dqi(v.w, inv_v, vzp)};
        *(bf16x4*)(vd + (size_t)c * 1024 + t0 + t4 * 4) = o;
    }

#pragma unroll
    for (int r = 0; r < 4; ++r) {
        int c = 16 * r + cr;
        float4 v = *(const float4*)(kg + (size_t)c * 1024 + t0 + t4 * 4);
        sT[t4 * 4 + 0][c] = (__bf16)dqi(v.x, inv_k, kzp);
        sT[t4 * 4 + 1][c] = (__bf16)dqi(v.y, inv_k, kzp);
        sT[t4 * 4 + 2][c] = (__bf16)dqi(v.z, inv_k, kzp);
        sT[t4 * 4 + 3][c] = (__bf16)dqi(v.w, inv_k, kzp);
    }
    __syncthreads();
    bf16x8 a0 = *(const bf16x8*)&sT[s][c0];
    bf16x8 a1 = *(const bf16x8*)&sT[s][c0 + 8];
    __bf16* kd = ki + ((size_t)bh * 1024 + t0 + s) * 64 + c0;
    *(bf16x8*)kd = a0;
    *(bf16x8*)(kd + 8) = a1;
}

// ---------------- attention: QBLK=128, 8 waves, dbuf K/V, 1 barrier/tile, in-register P ----------------
__global__ __launch_bounds__(512, 4) void attn5(const float* __restrict__ qkv,
                                                const __bf16* __restrict__ ki,
                                                const __bf16* __restrict__ vi,
                                                const float* __restrict__ pmm,
                                                __bf16* __restrict__ aT) {
    int f = blockIdx.x;
    int bh = (f & 7) * 8 + ((f >> 3) & 7);  // batch b = f&7 -> XCD b
    int tt = f >> 6;                        // 0..7
    int b = bh >> 3, hh = bh & 7;
    int t0 = tt * 128;
    const float* qg = qkv + (size_t)(b * 1536 + hh * 192) * 1024;
    const __bf16* kb = ki + (size_t)bh * 65536;
    const __bf16* vb = vi + (size_t)bh * 65536;
    int tid = threadIdx.x;

    __shared__ float sred[16];
    float mn0, mx0, mn1, mx1, mn2, mx2;
    red_mm8(pmm, 0, tid, sred, mn0, mx0);
    red_mm8(pmm, 1, tid, sred, mn1, mx1);
    red_mm8(pmm, 2, tid, sred, mn2, mx2);
    float qsc = fmaxf((mx0 - mn0) * (1.f / 255.f), 1e-8f), qzp = rintf(-mn0 / qsc);
    float ksc = fmaxf((mx1 - mn1) * (1.f / 255.f), 1e-8f);
    float vsc = fmaxf((mx2 - mn2) * (1.f / 255.f), 1e-8f);
    float inv_q = 1.f / qsc;
    float alpha2 = qsc * ksc * 0.125f * 1.4426950408889634f;  // alpha * log2(e)
    float thr = 11.5415603f / alpha2;                          // 8 nats in raw-score units

    __shared__ __bf16 sh[128][72];   // q stage -> output stage (P no longer passes through LDS)
    __shared__ __bf16 kS[2][4096];   // K tile (s,c), chunk-swizzled, double-buffered
    __shared__ __bf16 vS[2][4096];   // V tile (c,s), chunk-swizzled, double-buffered
    int l = tid & 63, w = tid >> 6;
    int lo = l & 15, hi = l >> 4;

    // staging geometry: thread -> row (0..63), one 16B chunk each for K and V
    int srow = tid >> 3, sc = tid & 7;
    int swz = (sc ^ (srow & 7)) << 3;
    const __bf16* kROW = kb + (size_t)srow * 64;          // + st*4096
    const __bf16* vROW = vb + (size_t)srow * 1024;        // + st*64
    int lx = lo & 7;
    int rc0 = (hi ^ lx) << 3;
    int rc1 = ((4 + hi) ^ lx) << 3;

    // in-register P exchange lanes: word (u>>1)=0 from srcA, =1 from srcB; sm select by hi>=2
    int srcA = ((l & 16) << 1) + lo;   // 32*(hi&1) + lo
    int srcB = srcA + 16;
    bool hiSel = (l >= 32);            // hi>>1

    // issue tile-0 loads early; hide under q staging
    bf16x8 kr = *(const bf16x8*)(kROW + sc * 8);
    bf16x8 vr = *(const bf16x8*)(vROW + sc * 8);

    // inline q stage: transpose + dequant to integer-valued bf16 (128 t x 64 c)
    {
        int c0 = (tid >> 5) * 4;     // 0..60
        int tl = tid & 31;
#pragma unroll
        for (int r = 0; r < 4; ++r) {
            int t = tl + 32 * r;
            float y0 = dqi(qg[(size_t)(c0 + 0) * 1024 + t0 + t], inv_q, qzp);
            float y1 = dqi(qg[(size_t)(c0 + 1) * 1024 + t0 + t], inv_q, qzp);
            float y2 = dqi(qg[(size_t)(c0 + 2) * 1024 + t0 + t], inv_q, qzp);
            float y3 = dqi(qg[(size_t)(c0 + 3) * 1024 + t0 + t], inv_q, qzp);
            bf16x4 o = {(__bf16)y0, (__bf16)y1, (__bf16)y2, (__bf16)y3};
            *(bf16x4*)&sh[t][c0] = o;
        }
    }
    __syncthreads();
    bf16x8 qf0 = *(const bf16x8*)&sh[16 * w + lo][hi * 8];
    bf16x8 qf1 = *(const bf16x8*)&sh[16 * w + lo][32 + hi * 8];
    // stage tile 0 (waits vmcnt via data dep)
    *(bf16x8*)(kS[0] + srow * 64 + swz) = kr;
    *(bf16x8*)(vS[0] + srow * 64 + swz) = vr;
    __syncthreads();   // q reads done + tile 0 staged

    f32x4 acc0 = {}, acc1 = {}, acc2 = {}, acc3 = {};
    float m_run = -1e30f, l_run = 0.f;

    for (int st = 0; st < 16; ++st) {
        const __bf16* kc = kS[st & 1];
        const __bf16* vc = vS[st & 1];
        if (st < 15) {   // T14: issue next-tile loads before compute
            kr = *(const bf16x8*)(kROW + (st + 1) * 4096 + sc * 8);
            vr = *(const bf16x8*)(vROW + (st + 1) * 64 + sc * 8);
        }

        // scores: D[s][t] = K·Q (raw integer dot products)
        f32x4 sf[4] = {};
        __builtin_amdgcn_s_setprio(1);
#pragma unroll
        for (int sm = 0; sm < 4; ++sm)
            sf[sm] = mfma16(*(const bf16x8*)(kc + (16 * sm + lo) * 64 + rc0), qf0, sf[sm]);
#pragma unroll
        for (int sm = 0; sm < 4; ++sm)
            sf[sm] = mfma16(*(const bf16x8*)(kc + (16 * sm + lo) * 64 + rc1), qf1, sf[sm]);
        __builtin_amdgcn_s_setprio(0);

        // online softmax in exp2 space (t = lane-local)
        float tm = -1e30f;
#pragma unroll
        for (int sm = 0; sm < 4; ++sm) {
            float a = fmaxf(sf[sm][0], sf[sm][1]);
            float c = fmaxf(sf[sm][2], sf[sm][3]);
            tm = fmaxf(tm, fmaxf(a, c));
        }
        tm = fmaxf(tm, __shfl_xor(tm, 16));
        tm = fmaxf(tm, __shfl_xor(tm, 32));
        if (!__all(tm <= m_run + thr)) {   // defer-max
            float mnew = fmaxf(m_run, tm);
            float fr = exp2i(alpha2 * (m_run - mnew));
            acc0 *= fr; acc1 *= fr; acc2 *= fr; acc3 *= fr;
            l_run *= fr;
            m_run = mnew;
        }
        float cc = -alpha2 * m_run;
        float ts = 0.f;
#pragma unroll
        for (int sm = 0; sm < 4; ++sm)
#pragma unroll
            for (int r = 0; r < 4; ++r) {
                float p = exp2i(fmaf(sf[sm][r], alpha2, cc));
                sf[sm][r] = p;
                ts += p;
            }
        ts += __shfl_xor(ts, 16);
        ts += __shfl_xor(ts, 32);
        l_run += ts;

        // P -> bf16 packed words (same (__bf16) rounding as before)
        unsigned w0a = pk2(sf[0][0], sf[0][1]), w0b = pk2(sf[0][2], sf[0][3]);
        unsigned w1a = pk2(sf[1][0], sf[1][1]), w1b = pk2(sf[1][2], sf[1][3]);
        unsigned w2a = pk2(sf[2][0], sf[2][1]), w2b = pk2(sf[2][2], sf[2][3]);
        unsigned w3a = pk2(sf[3][0], sf[3][1]), w3b = pk2(sf[3][2], sf[3][3]);

        // assemble PV B-frags in-register: word u of pf = W[sm=hi>>1][u&1] from lane
        // 32*(hi&1) + 16*(u>>1) + lo   (verified vs m89 C/D layout)
        union { unsigned u[4]; bf16x8 v; } pf0, pf1;
        {
            unsigned a0s = (unsigned)__shfl((int)w0a, srcA), b0s = (unsigned)__shfl((int)w1a, srcA);
            unsigned a1s = (unsigned)__shfl((int)w0b, srcA), b1s = (unsigned)__shfl((int)w1b, srcA);
            unsigned a2s = (unsigned)__shfl((int)w0a, srcB), b2s = (unsigned)__shfl((int)w1a, srcB);
            unsigned a3s = (unsigned)__shfl((int)w0b, srcB), b3s = (unsigned)__shfl((int)w1b, srcB);
            pf0.u[0] = hiSel ? b0s : a0s;
            pf0.u[1] = hiSel ? b1s : a1s;
            pf0.u[2] = hiSel ? b2s : a2s;
            pf0.u[3] = hiSel ? b3s : a3s;
            unsigned c0s = (unsigned)__shfl((int)w2a, srcA), d0s = (unsigned)__shfl((int)w3a, srcA);
            unsigned c1s = (unsigned)__shfl((int)w2b, srcA), d1s = (unsigned)__shfl((int)w3b, srcA);
            unsigned c2s = (unsigned)__shfl((int)w2a, srcB), d2s = (unsigned)__shfl((int)w3a, srcB);
            unsigned c3s = (unsigned)__shfl((int)w2b, srcB), d3s = (unsigned)__shfl((int)w3b, srcB);
            pf1.u[0] = hiSel ? d0s : c0s;
            pf1.u[1] = hiSel ? d1s : c1s;
            pf1.u[2] = hiSel ? d2s : c2s;
            pf1.u[3] = hiSel ? d3s : c3s;
        }

        // PV: D[c][t] += V·P
        __builtin_amdgcn_s_setprio(1);
        acc0 = mfma16(*(const bf16x8*)(vc + (lo) * 64 + rc0), pf0.v, acc0);
        acc1 = mfma16(*(const bf16x8*)(vc + (16 + lo) * 64 + rc0), pf0.v, acc1);
        acc2 = mfma16(*(const bf16x8*)(vc + (32 + lo) * 64 + rc0), pf0.v, acc2);
        acc3 = mfma16(*(const bf16x8*)(vc + (48 + lo) * 64 + rc0), pf0.v, acc3);
        acc0 = mfma16(*(const bf16x8*)(vc + (lo) * 64 + rc1), pf1.v, acc0);
        acc1 = mfma16(*(const bf16x8*)(vc + (16 + lo) * 64 + rc1), pf1.v, acc1);
        acc2 = mfma16(*(const bf16x8*)(vc + (32 + lo) * 64 + rc1), pf1.v, acc2);
        acc3 = mfma16(*(const bf16x8*)(vc + (48 + lo) * 64 + rc1), pf1.v, acc3);
        __builtin_amdgcn_s_setprio(0);

        if (st < 15) {   // write-late into the other buffer (readers finished at prev barrier)
            *(bf16x8*)(kS[(st + 1) & 1] + srow * 64 + swz) = kr;
            *(bf16x8*)(vS[(st + 1) & 1] + srow * 64 + swz) = vr;
        }
        __syncthreads();   // single barrier per tile
    }

    float rl = vsc / l_run;
    {
        bf16x4 o0 = {(__bf16)(acc0[0] * rl), (__bf16)(acc0[1] * rl), (__bf16)(acc0[2] * rl), (__bf16)(acc0[3] * rl)};
        bf16x4 o1 = {(__bf16)(acc1[0] * rl), (__bf16)(acc1[1] * rl), (__bf16)(acc1[2] * rl), (__bf16)(acc1[3] * rl)};
        bf16x4 o2 = {(__bf16)(acc2[0] * rl), (__bf16)(acc2[1] * rl), (__bf16)(acc2[2] * rl), (__bf16)(acc2[3] * rl)};
        bf16x4 o3 = {(__bf16)(acc3[0] * rl), (__bf16)(acc3[1] * rl), (__bf16)(acc3[2] * rl), (__bf16)(acc3[3] * rl)};
        *(bf16x4*)&sh[16 * w + lo][0  + hi * 4] = o0;
        *(bf16x4*)&sh[16 * w + lo][16 + hi * 4] = o1;
        *(bf16x4*)&sh[16 * w + lo][32 + hi * 4] = o2;
        *(bf16x4*)&sh[16 * w + lo][48 + hi * 4] = o3;
    }
    __syncthreads();
    __bf16* ap = aT + ((size_t)b * 1024 + t0 + (tid >> 2)) * 512 + hh * 64;
    bf16x8 v0 = *(const bf16x8*)&sh[tid >> 2][(tid & 3) * 8];
    bf16x8 v1 = *(const bf16x8*)&sh[tid >> 2][32 + (tid & 3) * 8];
    *(bf16x8*)(ap + (tid & 3) * 8) = v0;
    *(bf16x8*)(ap + 32 + (tid & 3) * 8) = v1;
}

// ---------------- fallback attention (fp32 qkv, used if ws too small) ----------------
__global__ __launch_bounds__(256) void attn_mfma(const float* __restrict__ qkv,
                                                 const float* __restrict__ pmm,
                                                 __bf16* __restrict__ aT) {
    int f = blockIdx.x;
    int bh = (f & 7) * 8 + ((f >> 3) & 7);
    int tt = f >> 6;
    int b = bh >> 3, hh = bh & 7;
    int t0 = tt * 64;
    const float* qg = qkv + (size_t)(b * 1536 + hh * 192) * 1024;
    const float* kg = qg + (size_t)64 * 1024;
    const float* vg = qg + (size_t)128 * 1024;
    int tid = threadIdx.x;

    __shared__ float sred[8];
    float mn0, mx0, mn1, mx1, mn2, mx2;
    red_mm(pmm, 0, tid, sred, mn0, mx0);
    red_mm(pmm, 1, tid, sred, mn1, mx1);
    red_mm(pmm, 2, tid, sred, mn2, mx2);
    float qsc = fmaxf((mx0 - mn0) * (1.f / 255.f), 1e-8f), qzp = rintf(-mn0 / qsc);
    float ksc = fmaxf((mx1 - mn1) * (1.f / 255.f), 1e-8f), kzp = rintf(-mn1 / ksc);
    float vsc = fmaxf((mx2 - mn2) * (1.f / 255.f), 1e-8f), vzp = rintf(-mn2 / vsc);
    float inv_q = 1.f / qsc, inv_k = 1.f / ksc, inv_v = 1.f / vsc;
    float alpha = qsc * ksc * 0.125f;

    __shared__ __bf16 qT[64][72];
    __shared__ __bf16 kT[64][72];
    __shared__ __bf16 vL[64][72];
    __shared__ __bf16 pL[4][16][72];

    int l = tid & 63, w = tid >> 6;
    int lo = l & 15, hi = l >> 4;
    int c0 = (tid >> 4) * 4;
    int tl = tid & 15;

#pragma unroll
    for (int r = 0; r < 4; ++r) {
        int t = tl + 16 * r;
        float y0 = dqi(qg[(size_t)(c0 + 0) * 1024 + t0 + t], inv_q, qzp);
        float y1 = dqi(qg[(size_t)(c0 + 1) * 1024 + t0 + t], inv_q, qzp);
        float y2 = dqi(qg[(size_t)(c0 + 2) * 1024 + t0 + t], inv_q, qzp);
        float y3 = dqi(qg[(size_t)(c0 + 3) * 1024 + t0 + t], inv_q, qzp);
        bf16x4 o = {(__bf16)y0, (__bf16)y1, (__bf16)y2, (__bf16)y3};
        *(bf16x4*)&qT[t][c0] = o;
    }
    __syncthreads();
    bf16x8 qf0 = *(const bf16x8*)&qT[16 * w + lo][hi * 8];
    bf16x8 qf1 = *(const bf16x8*)&qT[16 * w + lo][32 + hi * 8];

    f32x4 acc0 = {}, acc1 = {}, acc2 = {}, acc3 = {};
    float m_run = -1e30f, l_run = 0.f;

    for (int st = 0; st < 16; ++st) {
        int s0 = st * 64;
        __syncthreads();
#pragma unroll
        for (int r = 0; r < 4; ++r) {
            int srow = tl + 16 * r;
            float y0 = dqi(kg[(size_t)(c0 + 0) * 1024 + s0 + srow], inv_k, kzp);
            float y1 = dqi(kg[(size_t)(c0 + 1) * 1024 + s0 + srow], inv_k, kzp);
            float y2 = dqi(kg[(size_t)(c0 + 2) * 1024 + s0 + srow], inv_k, kzp);
            float y3 = dqi(kg[(size_t)(c0 + 3) * 1024 + s0 + srow], inv_k, kzp);
            bf16x4 ok = {(__bf16)y0, (__bf16)y1, (__bf16)y2, (__bf16)y3};
            *(bf16x4*)&kT[srow][c0] = ok;
            int c = (tid >> 4) + 16 * r;
            float4 vv = *(const float4*)(vg + (size_t)c * 1024 + s0 + (tid & 15) * 4);
            bf16x4 ov = {(__bf16)dqi(vv.x, inv_v, vzp), (__bf16)dqi(vv.y, inv_v, vzp),
                         (__bf16)dqi(vv.z, inv_v, vzp), (__bf16)dqi(vv.w, inv_v, vzp)};
            *(bf16x4*)&vL[c][(tid & 15) * 4] = ov;
        }
        __syncthreads();

        f32x4 sf[4] = {};
#pragma unroll
        for (int sm = 0; sm < 4; ++sm)
            sf[sm] = mfma16(*(const bf16x8*)&kT[16 * sm + lo][hi * 8], qf0, sf[sm]);
#pragma unroll
        for (int sm = 0; sm < 4; ++sm)
            sf[sm] = mfma16(*(const bf16x8*)&kT[16 * sm + lo][32 + hi * 8], qf1, sf[sm]);

        float tm = -1e30f;
#pragma unroll
        for (int sm = 0; sm < 4; ++sm)
#pragma unroll
            for (int r = 0; r < 4; ++r) { sf[sm][r] *= alpha; tm = fmaxf(tm, sf[sm][r]); }
        tm = fmaxf(tm, __shfl_xor(tm, 16));
        tm = fmaxf(tm, __shfl_xor(tm, 32));
        float mnew = fmaxf(m_run, tm);
        float ts = 0.f;
#pragma unroll
        for (int sm = 0; sm < 4; ++sm)
#pragma unroll
            for (int r = 0; r < 4; ++r) {
                float p = __expf(sf[sm][r] - mnew);
                sf[sm][r] = p;
                ts += p;
            }
        ts += __shfl_xor(ts, 16);
        ts += __shfl_xor(ts, 32);
        float fr = __expf(m_run - mnew);
        l_run = l_run * fr + ts;
        m_run = mnew;
        acc0 *= fr; acc1 *= fr; acc2 *= fr; acc3 *= fr;

#pragma unroll
        for (int sm = 0; sm < 4; ++sm) {
            bf16x4 pb = {(__bf16)sf[sm][0], (__bf16)sf[sm][1], (__bf16)sf[sm][2], (__bf16)sf[sm][3]};
            *(bf16x4*)&pL[w][lo][16 * sm + hi * 4] = pb;
        }
        bf16x8 pf0 = *(const bf16x8*)&pL[w][lo][hi * 8];
        bf16x8 pf1 = *(const bf16x8*)&pL[w][lo][32 + hi * 8];
        acc0 = mfma16(*(const bf16x8*)&vL[lo][hi * 8], pf0, acc0);
        acc1 = mfma16(*(const bf16x8*)&vL[16 + lo][hi * 8], pf0, acc1);
        acc2 = mfma16(*(const bf16x8*)&vL[32 + lo][hi * 8], pf0, acc2);
        acc3 = mfma16(*(const bf16x8*)&vL[48 + lo][hi * 8], pf0, acc3);
        acc0 = mfma16(*(const bf16x8*)&vL[lo][32 + hi * 8], pf1, acc0);
        acc1 = mfma16(*(const bf16x8*)&vL[16 + lo][32 + hi * 8], pf1, acc1);
        acc2 = mfma16(*(const bf16x8*)&vL[32 + lo][32 + hi * 8], pf1, acc2);
        acc3 = mfma16(*(const bf16x8*)&vL[48 + lo][32 + hi * 8], pf1, acc3);
    }

    float rl = vsc / l_run;
    __syncthreads();
    {
        bf16x4 o0 = {(__bf16)(acc0[0] * rl), (__bf16)(acc0[1] * rl), (__bf16)(acc0[2] * rl), (__bf16)(acc0[3] * rl)};
        bf16x4 o1 = {(__bf16)(acc1[0] * rl), (__bf16)(acc1[1] * rl), (__bf16)(acc1[2] * rl), (__bf16)(acc1[3] * rl)};
        bf16x4 o2 = {(__bf16)(acc2[0] * rl), (__bf16)(acc2[1] * rl), (__bf16)(acc2[2] * rl), (__bf16)(acc2[3] * rl)};
        bf16x4 o3 = {(__bf16)(acc3[0] * rl), (__bf16)(acc3[1] * rl), (__bf16)(acc3[2] * rl), (__bf16)(acc3[3] * rl)};
        *(bf16x4*)&qT[16 * w + lo][0  + hi * 4] = o0;
        *(bf16x4*)&qT[16 * w + lo][16 + hi * 4] = o1;
        *(bf16x4*)&qT[16 * w + lo][32 + hi * 4] = o2;
        *(bf16x4*)&qT[16 * w + lo][48 + hi * 4] = o3;
    }
    __syncthreads();
    __bf16* ap = aT + ((size_t)b * 1024 + t0 + (tid >> 2)) * 512 + hh * 64;
    bf16x8 v0 = *(const bf16x8*)&qT[tid >> 2][(tid & 3) * 8];
    bf16x8 v1 = *(const bf16x8*)&qT[tid >> 2][32 + (tid & 3) * 8];
    *(bf16x8*)(ap + (tid & 3) * 8) = v0;
    *(bf16x8*)(ap + 32 + (tid & 3) * 8) = v1;
}

extern "C" void kernel_launch(void* const* d_in, const int* in_sizes, int n_in,
                              void* d_out, int out_size, void* d_ws, size_t ws_size,
                              hipStream_t stream) {
    const float* x      = (const float*)d_in[0];
    const float* gn_w   = (const float*)d_in[1];
    const float* gn_b   = (const float*)d_in[2];
    const float* qkv_w  = (const float*)d_in[3];
    const float* qkv_b  = (const float*)d_in[4];
    const float* proj_w = (const float*)d_in[5];
    const float* proj_b = (const float*)d_in[6];
    char* ws = (char*)d_ws;
    float*    qkv = (float*)(ws + QKV_OFF);
    __bf16*   hT  = (__bf16*)(ws + HT_OFF);   // hT, later reused as aT
    __bf16*   wq  = (__bf16*)(ws + WQ_OFF);
    __bf16*   wp  = (__bf16*)(ws + WP_OFF);
    float*    pmm = (float*)(ws + MM_OFF);    // 3 x 256 x {mn,mx} partials
    float*    gst = (float*)(ws + GST_OFF);   // mean[256], rstd[256]
    __bf16*   ki  = (__bf16*)(ws + KI_OFF);
    __bf16*   vi  = (__bf16*)(ws + VI_OFF);
    float* out = (float*)d_out;

    gnstats<<<1280, 256, 0, stream>>>(x, qkv_w, wq, proj_w, wp, gst);
    gnapply<<<256, 256, 0, stream>>>(x, gn_w, gn_b, gst, hT);
    mgemm5<128, 12, true, false><<<768, 256, 0, stream>>>(wq, hT, qkv_b, nullptr, qkv, 1536, pmm);
    if (ws_size >= NEED_NEW) {
        quant_kv<<<1024, 256, 0, stream>>>(qkv, pmm, ki, vi);
        attn5<<<512, 512, 0, stream>>>(qkv, ki, vi, pmm, hT);
    } else {
        attn_mfma<<<1024, 256, 0, stream>>>(qkv, pmm, hT);
    }
    mgemm5<64, 8, false, true><<<512, 256, 0, stream>>>(wp, hT, proj_b, x, out, 512, nullptr);
}

// Round 14
// 93.909 us; speedup vs baseline: 1.0709x; 1.0709x over previous
//
#include <hip/hip_runtime.h>

typedef __attribute__((ext_vector_type(8))) __bf16 bf16x8;
typedef __attribute__((ext_vector_type(4))) __bf16 bf16x4;
typedef __attribute__((ext_vector_type(4))) float  f32x4;

// Problem: x (8,512,32,32) fp32 -> B=8, C=512, T=1024; 32 groups; 8 heads (ch=64)

// ws layout (bytes)
static constexpr size_t QKV_OFF = 0;                     // fp32 (8,1536,1024) 48MB
static constexpr size_t HT_OFF  = 50331648;              // bf16 (8,1024,512) 8MB: hT then aT
static constexpr size_t WQ_OFF  = HT_OFF + 8388608;      // bf16 (1536,512)
static constexpr size_t WP_OFF  = WQ_OFF + 1572864;      // bf16 (512,512)
static constexpr size_t MM_OFF  = WP_OFF + 524288;       // pmm partials (6144B) + gn stats (2048B)
static constexpr size_t GST_OFF = MM_OFF + 6144;         // mean[256], rstd[256] f32
static constexpr size_t KI_OFF  = MM_OFF + 8192;         // bf16 (64,1024,64) 8MB
static constexpr size_t VI_OFF  = KI_OFF + 8388608;      // bf16 (64,64,1024) 8MB
static constexpr size_t NEED_NEW = VI_OFF + 8388608;

// integer-valued dequant core: clip(rint(x/s)+zp,0,255)-zp == clip(rint(x/s), -zp, 255-zp)
__device__ __forceinline__ float dqi(float x, float inv_s, float zp) {
    float y = rintf(x * inv_s);
    return fminf(fmaxf(y, -zp), 255.0f - zp);
}
__device__ __forceinline__ f32x4 mfma16(bf16x8 a, bf16x8 b, f32x4 c) {
    return __builtin_amdgcn_mfma_f32_16x16x32_bf16(a, b, c, 0, 0, 0);
}
__device__ __forceinline__ float exp2i(float x) {  // raw v_exp_f32 (2^x)
    float r;
    asm("v_exp_f32 %0, %1" : "=v"(r) : "v"(x));
    return r;
}
__device__ __forceinline__ void glds16(const __bf16* g, __bf16* l) {
    __builtin_amdgcn_global_load_lds((const __attribute__((address_space(1))) void*)g,
                                     (__attribute__((address_space(3))) void*)l, 16, 0, 0);
}
template <int N> __device__ __forceinline__ void waitv() {
    asm volatile("s_waitcnt vmcnt(%0)" :: "n"(N) : "memory");
}
__device__ __forceinline__ void bar_raw() {
    asm volatile("s_barrier" ::: "memory");
}

// reduce pmm[id][256][2] partials -> (mn, mx). 256-thread version.
__device__ __forceinline__ void red_mm(const float* __restrict__ pmm, int id, int tid,
                                       float* sred, float& mn_out, float& mx_out) {
    float mn = pmm[id * 512 + tid * 2];
    float mx = pmm[id * 512 + tid * 2 + 1];
#pragma unroll
    for (int m = 1; m < 64; m <<= 1) {
        mn = fminf(mn, __shfl_xor(mn, m));
        mx = fmaxf(mx, __shfl_xor(mx, m));
    }
    if ((tid & 63) == 0) { sred[(tid >> 6) * 2] = mn; sred[(tid >> 6) * 2 + 1] = mx; }
    __syncthreads();
    mn = fminf(fminf(sred[0], sred[2]), fminf(sred[4], sred[6]));
    mx = fmaxf(fmaxf(sred[1], sred[3]), fmaxf(sred[5], sred[7]));
    __syncthreads();
    mn_out = fminf(mn, 0.0f);
    mx_out = fmaxf(mx, 0.0f);
}

// 512-thread version (slots read twice; harmless for min/max)
__device__ __forceinline__ void red_mm8(const float* __restrict__ pmm, int id, int tid,
                                        float* sred, float& mn_out, float& mx_out) {
    int slot = tid & 255;
    float mn = pmm[id * 512 + slot * 2];
    float mx = pmm[id * 512 + slot * 2 + 1];
#pragma unroll
    for (int m = 1; m < 64; m <<= 1) {
        mn = fminf(mn, __shfl_xor(mn, m));
        mx = fmaxf(mx, __shfl_xor(mx, m));
    }
    if ((tid & 63) == 0) { sred[(tid >> 6) * 2] = mn; sred[(tid >> 6) * 2 + 1] = mx; }
    __syncthreads();
    float a = fminf(fminf(sred[0], sred[2]), fminf(sred[4], sred[6]));
    float b = fminf(fminf(sred[8], sred[10]), fminf(sred[12], sred[14]));
    mn = fminf(a, b);
    a = fmaxf(fmaxf(sred[1], sred[3]), fmaxf(sred[5], sred[7]));
    b = fmaxf(fmaxf(sred[9], sred[11]), fmaxf(sred[13], sred[15]));
    mx = fmaxf(a, b);
    __syncthreads();
    mn_out = fminf(mn, 0.0f);
    mx_out = fmaxf(mx, 0.0f);
}

// ---------------- gnstats: weight fp32->bf16 convert + per-(b,g) mean/rstd ----------------
__global__ __launch_bounds__(256) void gnstats(const float* __restrict__ x,
                                               const float* __restrict__ qw,
                                               __bf16* __restrict__ wq,
                                               const float* __restrict__ pw,
                                               __bf16* __restrict__ wp,
                                               float* __restrict__ gst) {
    int bid = blockIdx.x, tid = threadIdx.x;
    if (bid < 1024) {
        if (bid < 768) {
            int i = bid * 256 + tid;
            float4 v = ((const float4*)qw)[i];
            bf16x4 o = {(__bf16)v.x, (__bf16)v.y, (__bf16)v.z, (__bf16)v.w};
            ((bf16x4*)wq)[i] = o;
        } else {
            int i = (bid - 768) * 256 + tid;
            float4 v = ((const float4*)pw)[i];
            bf16x4 o = {(__bf16)v.x, (__bf16)v.y, (__bf16)v.z, (__bf16)v.w};
            ((bf16x4*)wp)[i] = o;
        }
        return;
    }
    int blk = bid - 1024;
    int b = blk >> 5, g = blk & 31;
    const float* xp = x + (size_t)(b * 512 + g * 16) * 1024;

    float sum = 0.f, ss = 0.f;
#pragma unroll
    for (int i = 0; i < 16; ++i) {
        float4 v = *(const float4*)(xp + (size_t)i * 1024 + tid * 4);
        sum += v.x + v.y + v.z + v.w;
        ss  += v.x * v.x + v.y * v.y + v.z * v.z + v.w * v.w;
    }
#pragma unroll
    for (int m = 1; m < 64; m <<= 1) {
        sum += __shfl_xor(sum, m);
        ss  += __shfl_xor(ss, m);
    }
    __shared__ float s1[4], s2[4];
    int wid = tid >> 6;
    if ((tid & 63) == 0) { s1[wid] = sum; s2[wid] = ss; }
    __syncthreads();
    if (tid == 0) {
        sum = s1[0] + s1[1] + s1[2] + s1[3];
        ss  = s2[0] + s2[1] + s2[2] + s2[3];
        float mean = sum * (1.0f / 16384.0f);
        float var  = ss * (1.0f / 16384.0f) - mean * mean;
        gst[blk]       = mean;
        gst[256 + blk] = rsqrtf(var + 1e-5f);
    }
}

// ---------------- gnapply: t-major normalize + transpose, coalesced both sides ----------------
__global__ __launch_bounds__(256) void gnapply(const float* __restrict__ x,
                                               const float* __restrict__ w,
                                               const float* __restrict__ bv,
                                               const float* __restrict__ gst,
                                               __bf16* __restrict__ hT) {
    int f = blockIdx.x;
    int b = f & 7, ts = f >> 3;
    int t0 = ts * 32;
    int tid = threadIdx.x;

    __shared__ __bf16 sH[32][520];
    int cl = tid >> 3;
    int tl = (tid & 7) * 4;

#pragma unroll
    for (int ci = 0; ci < 16; ++ci) {
        int c = ci * 32 + cl;
        int g = c >> 4;
        float mean = gst[b * 32 + g];
        float rstd = gst[256 + b * 32 + g];
        float wc = w[c] * rstd, bc = bv[c];
        float4 v = *(const float4*)(x + ((size_t)(b * 512 + c)) * 1024 + t0 + tl);
        sH[tl + 0][c] = (__bf16)((v.x - mean) * wc + bc);
        sH[tl + 1][c] = (__bf16)((v.y - mean) * wc + bc);
        sH[tl + 2][c] = (__bf16)((v.z - mean) * wc + bc);
        sH[tl + 3][c] = (__bf16)((v.w - mean) * wc + bc);
    }
    __syncthreads();
    int lane = tid & 63, wv = tid >> 6;
#pragma unroll
    for (int it = 0; it < 8; ++it) {
        int row = it * 4 + wv;
        bf16x8 o = *(const bf16x8*)&sH[row][lane * 8];
        *(bf16x8*)(hT + ((size_t)(b * 1024 + t0 + row)) * 512 + lane * 8) = o;
    }
}

// ---------------- MFMA GEMM v5: BK=64 conflict-free swizzle + counted-vmcnt dbuf, NO atomics ----------------
template <int MTILE, int MOT, bool MINMAX, bool RESID>
__global__ __launch_bounds__(256, 2) void mgemm5(const __bf16* __restrict__ A,   // [M][512]
                                                 const __bf16* __restrict__ Bt,  // [8][1024][512]
                                                 const float* __restrict__ bias,
                                                 const float* __restrict__ resid,
                                                 float* __restrict__ out,
                                                 int M, float* __restrict__ pmm) {
    constexpr int NF  = (MTILE == 128) ? 4 : 2;
    constexpr int ASZ = MTILE * 64;
    constexpr int BSZ = 128 * 64;
    constexpr int LA  = MTILE / 32;
    constexpr int L   = LA + 4;
    constexpr int STG = 2 * (ASZ + BSZ) * 2;
    constexpr int CSB = 64 * 132 * 4;
    __shared__ __attribute__((aligned(16))) char smem_raw[(STG > CSB) ? STG : CSB];
    __bf16* sA0 = (__bf16*)smem_raw;
    __bf16* sA1 = sA0 + ASZ;
    __bf16* sB0 = sA1 + ASZ;
    __bf16* sB1 = sB0 + BSZ;
    __shared__ float smn[4], smx[4];

    int tid = threadIdx.x;
    int l = tid & 63, w = tid >> 6;
    int lo = l & 15, hi = l >> 4;

    int f = blockIdx.x;
    constexpr int NWG = MOT * 64;
    int wg = (f & 7) * (NWG / 8) + (f >> 3);
    int mo = wg % MOT, nb = wg / MOT;
    int nt = nb & 7, b = nb >> 3;

    const __bf16* Ap = A + (size_t)mo * MTILE * 512;
    const __bf16* Bp = Bt + ((size_t)b * 1024 + (size_t)nt * 128) * 512;
    int m0 = (MTILE == 128) ? (w >> 1) * 64 : 0;
    int n0 = (MTILE == 128) ? (w & 1) * 64 : w * 32;
    f32x4 acc[4][NF] = {};
    int scd = tid & 7;

    auto STAGE = [&](__bf16* dA, __bf16* dB, int k0) {
#pragma unroll
        for (int p = 0; p < LA; ++p) {
            int lin = p * 2048 + tid * 8;
            int row = lin >> 6;
            glds16(Ap + (size_t)row * 512 + k0 + ((scd ^ (row & 7)) << 3), dA + lin);
        }
#pragma unroll
        for (int p = 0; p < 4; ++p) {
            int lin = p * 2048 + tid * 8;
            int row = lin >> 6;
            glds16(Bp + (size_t)row * 512 + k0 + ((scd ^ (row & 7)) << 3), dB + lin);
        }
    };
    auto COMPUTE = [&](const __bf16* cA, const __bf16* cB) {
#pragma unroll
        for (int kk = 0; kk < 2; ++kk) {
            int rch = ((kk * 4 + hi) ^ (lo & 7)) << 3;
            bf16x8 af[4], bfr[NF];
#pragma unroll
            for (int i = 0; i < 4; ++i) af[i] = *(const bf16x8*)&cA[(m0 + 16 * i + lo) * 64 + rch];
#pragma unroll
            for (int j = 0; j < NF; ++j) bfr[j] = *(const bf16x8*)&cB[(n0 + 16 * j + lo) * 64 + rch];
#pragma unroll
            for (int i = 0; i < 4; ++i)
#pragma unroll
                for (int j = 0; j < NF; ++j) acc[i][j] = mfma16(af[i], bfr[j], acc[i][j]);
        }
    };

    STAGE(sA0, sB0, 0);
#pragma unroll
    for (int kp = 0; kp < 8; kp += 2) {
        if (kp + 1 < 8) { STAGE(sA1, sB1, (kp + 1) * 64); waitv<L>(); } else { waitv<0>(); }
        bar_raw();
        COMPUTE(sA0, sB0);
        bar_raw();
        if (kp + 2 < 8) { STAGE(sA0, sB0, (kp + 2) * 64); waitv<L>(); } else { waitv<0>(); }
        bar_raw();
        COMPUTE(sA1, sB1);
        bar_raw();
    }

    float* cs = (float*)smem_raw;
    float mn = 1e30f, mx = -1e30f;
    constexpr int NH = (MTILE == 128) ? 2 : 1;
#pragma unroll
    for (int h = 0; h < NH; ++h) {
        __syncthreads();
        if (MTILE == 64 || (w >> 1) == h) {
#pragma unroll
            for (int i = 0; i < 4; ++i)
#pragma unroll
                for (int r = 0; r < 4; ++r) {
                    int rl = 16 * i + hi * 4 + r;
                    float bi = bias[mo * MTILE + h * 64 + rl];
#pragma unroll
                    for (int j = 0; j < NF; ++j)
                        cs[rl * 132 + n0 + 16 * j + lo] = acc[i][j][r] + bi;
                }
        }
        __syncthreads();
#pragma unroll
        for (int it = 0; it < 8; ++it) {
            int lin = it * 256 + tid;
            int rr = lin >> 5, cc = (lin & 31) << 2;
            float4 v = *(const float4*)&cs[rr * 132 + cc];
            if (MINMAX) {
                mn = fminf(mn, fminf(fminf(v.x, v.y), fminf(v.z, v.w)));
                mx = fmaxf(mx, fmaxf(fmaxf(v.x, v.y), fmaxf(v.z, v.w)));
            }
            int grow = mo * MTILE + h * 64 + rr;
            size_t gaddr = ((size_t)b * M + grow) * 1024 + nt * 128 + cc;
            if (RESID) {
                float4 rv = *(const float4*)&resid[gaddr];
                v.x += rv.x; v.y += rv.y; v.z += rv.z; v.w += rv.w;
            }
            *(float4*)&out[gaddr] = v;
        }
    }

    if (MINMAX) {
#pragma unroll
        for (int msk = 1; msk < 64; msk <<= 1) {
            mn = fminf(mn, __shfl_xor(mn, msk));
            mx = fmaxf(mx, __shfl_xor(mx, msk));
        }
        if (l == 0) { smn[w] = mn; smx[w] = mx; }
        __syncthreads();
        if (tid == 0) {
            mn = fminf(fminf(smn[0], smn[1]), fminf(smn[2], smn[3]));
            mx = fmaxf(fmaxf(smx[0], smx[1]), fmaxf(smx[2], smx[3]));
            int id = mo >> 2;
            int slot = nb * 4 + (mo & 3);
            pmm[id * 512 + slot * 2]     = mn;
            pmm[id * 512 + slot * 2 + 1] = mx;
        }
    }
}

// ---------------- quant K/V pass, XCD-aligned: batch b on XCD b ----------------
__global__ __launch_bounds__(256) void quant_kv(const float* __restrict__ qkv,
                                                const float* __restrict__ pmm,
                                                __bf16* __restrict__ ki,
                                                __bf16* __restrict__ vi) {
    int f = blockIdx.x;
    int b = f & 7;
    int r2 = f >> 3;
    int hh = r2 & 7, tt = r2 >> 3;
    int bh = b * 8 + hh;
    int t0 = tt * 64;
    const float* kg = qkv + ((size_t)(b * 1536 + hh * 192) + 64) * 1024;
    const float* vg = kg + 65536;
    int tid = threadIdx.x;

    __shared__ float sred[8];
    float mn1, mx1, mn2, mx2;
    red_mm(pmm, 1, tid, sred, mn1, mx1);
    red_mm(pmm, 2, tid, sred, mn2, mx2);
    float ksc = fmaxf((mx1 - mn1) * (1.f / 255.f), 1e-8f), kzp = rintf(-mn1 / ksc);
    float vsc = fmaxf((mx2 - mn2) * (1.f / 255.f), 1e-8f), vzp = rintf(-mn2 / vsc);
    float inv_k = 1.f / ksc, inv_v = 1.f / vsc;

    __shared__ __bf16 sT[64][68];
    int cr = tid >> 4, t4 = tid & 15;
    int s = tid >> 2, c0 = (tid & 3) * 16;

    __bf16* vd = vi + (size_t)bh * 65536;
#pragma unroll
    for (int r = 0; r < 4; ++r) {
        int c = 16 * r + cr;
        float4 v = *(const float4*)(vg + (size_t)c * 1024 + t0 + t4 * 4);
        bf16x4 o = {(__bf16)dqi(v.x, inv_v, vzp), (__bf16)dqi(v.y, inv_v, vzp),
                    (__bf16)dqi(v.z, inv_v, vzp), (__bf16)dqi(v.w, inv_v, vzp)};
        *(bf16x4*)(vd + (size_t)c * 1024 + t0 + t4 * 4) = o;
    }

#pragma unroll
    for (int r = 0; r < 4; ++r) {
        int c = 16 * r + cr;
        float4 v = *(const float4*)(kg + (size_t)c * 1024 + t0 + t4 * 4);
        sT[t4 * 4 + 0][c] = (__bf16)dqi(v.x, inv_k, kzp);
        sT[t4 * 4 + 1][c] = (__bf16)dqi(v.y, inv_k, kzp);
        sT[t4 * 4 + 2][c] = (__bf16)dqi(v.z, inv_k, kzp);
        sT[t4 * 4 + 3][c] = (__bf16)dqi(v.w, inv_k, kzp);
    }
    __syncthreads();
    bf16x8 a0 = *(const bf16x8*)&sT[s][c0];
    bf16x8 a1 = *(const bf16x8*)&sT[s][c0 + 8];
    __bf16* kd = ki + ((size_t)bh * 1024 + t0 + s) * 64 + c0;
    *(bf16x8*)kd = a0;
    *(bf16x8*)(kd + 8) = a1;
}

// ---------------- attention: QBLK=128, 8 waves, dbuf K/V, 1 barrier/tile ----------------
__global__ __launch_bounds__(512, 4) void attn5(const float* __restrict__ qkv,
                                                const __bf16* __restrict__ ki,
                                                const __bf16* __restrict__ vi,
                                                const float* __restrict__ pmm,
                                                __bf16* __restrict__ aT) {
    int f = blockIdx.x;
    int bh = (f & 7) * 8 + ((f >> 3) & 7);  // batch b = f&7 -> XCD b
    int tt = f >> 6;                        // 0..7
    int b = bh >> 3, hh = bh & 7;
    int t0 = tt * 128;
    const float* qg = qkv + (size_t)(b * 1536 + hh * 192) * 1024;
    const __bf16* kb = ki + (size_t)bh * 65536;
    const __bf16* vb = vi + (size_t)bh * 65536;
    int tid = threadIdx.x;

    __shared__ float sred[16];
    float mn0, mx0, mn1, mx1, mn2, mx2;
    red_mm8(pmm, 0, tid, sred, mn0, mx0);
    red_mm8(pmm, 1, tid, sred, mn1, mx1);
    red_mm8(pmm, 2, tid, sred, mn2, mx2);
    float qsc = fmaxf((mx0 - mn0) * (1.f / 255.f), 1e-8f), qzp = rintf(-mn0 / qsc);
    float ksc = fmaxf((mx1 - mn1) * (1.f / 255.f), 1e-8f);
    float vsc = fmaxf((mx2 - mn2) * (1.f / 255.f), 1e-8f);
    float inv_q = 1.f / qsc;
    float alpha2 = qsc * ksc * 0.125f * 1.4426950408889634f;  // alpha * log2(e)
    float thr = 11.5415603f / alpha2;                          // 8 nats in raw-score units

    __shared__ __bf16 sh[128][72];   // q stage -> per-wave P -> output stage
    __shared__ __bf16 kS[2][4096];   // K tile (s,c), chunk-swizzled, double-buffered
    __shared__ __bf16 vS[2][4096];   // V tile (c,s), chunk-swizzled, double-buffered
    int l = tid & 63, w = tid >> 6;
    int lo = l & 15, hi = l >> 4;

    // staging geometry: thread -> row (0..63), one 16B chunk each for K and V
    int srow = tid >> 3, sc = tid & 7;
    int swz = (sc ^ (srow & 7)) << 3;
    const __bf16* kROW = kb + (size_t)srow * 64;          // + st*4096
    const __bf16* vROW = vb + (size_t)srow * 1024;        // + st*64
    int lx = lo & 7;
    int rc0 = (hi ^ lx) << 3;
    int rc1 = ((4 + hi) ^ lx) << 3;

    // issue tile-0 loads early; hide under q staging
    bf16x8 kr = *(const bf16x8*)(kROW + sc * 8);
    bf16x8 vr = *(const bf16x8*)(vROW + sc * 8);

    // inline q stage: transpose + dequant to integer-valued bf16 (128 t x 64 c)
    {
        int c0 = (tid >> 5) * 4;     // 0..60
        int tl = tid & 31;
#pragma unroll
        for (int r = 0; r < 4; ++r) {
            int t = tl + 32 * r;
            float y0 = dqi(qg[(size_t)(c0 + 0) * 1024 + t0 + t], inv_q, qzp);
            float y1 = dqi(qg[(size_t)(c0 + 1) * 1024 + t0 + t], inv_q, qzp);
            float y2 = dqi(qg[(size_t)(c0 + 2) * 1024 + t0 + t], inv_q, qzp);
            float y3 = dqi(qg[(size_t)(c0 + 3) * 1024 + t0 + t], inv_q, qzp);
            bf16x4 o = {(__bf16)y0, (__bf16)y1, (__bf16)y2, (__bf16)y3};
            *(bf16x4*)&sh[t][c0] = o;
        }
    }
    __syncthreads();
    bf16x8 qf0 = *(const bf16x8*)&sh[16 * w + lo][hi * 8];
    bf16x8 qf1 = *(const bf16x8*)&sh[16 * w + lo][32 + hi * 8];
    // stage tile 0 (waits vmcnt via data dep)
    *(bf16x8*)(kS[0] + srow * 64 + swz) = kr;
    *(bf16x8*)(vS[0] + srow * 64 + swz) = vr;
    __syncthreads();   // q reads done + tile 0 staged

    f32x4 acc0 = {}, acc1 = {}, acc2 = {}, acc3 = {};
    float m_run = -1e30f, l_run = 0.f;

    for (int st = 0; st < 16; ++st) {
        const __bf16* kc = kS[st & 1];
        const __bf16* vc = vS[st & 1];
        if (st < 15) {   // T14: issue next-tile loads before compute
            kr = *(const bf16x8*)(kROW + (st + 1) * 4096 + sc * 8);
            vr = *(const bf16x8*)(vROW + (st + 1) * 64 + sc * 8);
        }

        // scores: D[s][t] = K·Q (raw integer dot products)
        f32x4 sf[4] = {};
        __builtin_amdgcn_s_setprio(1);
#pragma unroll
        for (int sm = 0; sm < 4; ++sm)
            sf[sm] = mfma16(*(const bf16x8*)(kc + (16 * sm + lo) * 64 + rc0), qf0, sf[sm]);
#pragma unroll
        for (int sm = 0; sm < 4; ++sm)
            sf[sm] = mfma16(*(const bf16x8*)(kc + (16 * sm + lo) * 64 + rc1), qf1, sf[sm]);
        __builtin_amdgcn_s_setprio(0);

        // online softmax in exp2 space (t = lane-local)
        float tm = -1e30f;
#pragma unroll
        for (int sm = 0; sm < 4; ++sm) {
            float a = fmaxf(sf[sm][0], sf[sm][1]);
            float c = fmaxf(sf[sm][2], sf[sm][3]);
            tm = fmaxf(tm, fmaxf(a, c));
        }
        tm = fmaxf(tm, __shfl_xor(tm, 16));
        tm = fmaxf(tm, __shfl_xor(tm, 32));
        if (!__all(tm <= m_run + thr)) {   // defer-max
            float mnew = fmaxf(m_run, tm);
            float fr = exp2i(alpha2 * (m_run - mnew));
            acc0 *= fr; acc1 *= fr; acc2 *= fr; acc3 *= fr;
            l_run *= fr;
            m_run = mnew;
        }
        float cc = -alpha2 * m_run;
        float ts = 0.f;
#pragma unroll
        for (int sm = 0; sm < 4; ++sm)
#pragma unroll
            for (int r = 0; r < 4; ++r) {
                float p = exp2i(fmaf(sf[sm][r], alpha2, cc));
                sf[sm][r] = p;
                ts += p;
            }
        ts += __shfl_xor(ts, 16);
        ts += __shfl_xor(ts, 32);
        l_run += ts;

        // P -> LDS (wave-private rows)
#pragma unroll
        for (int sm = 0; sm < 4; ++sm) {
            bf16x4 pb = {(__bf16)sf[sm][0], (__bf16)sf[sm][1], (__bf16)sf[sm][2], (__bf16)sf[sm][3]};
            *(bf16x4*)&sh[16 * w + lo][16 * sm + hi * 4] = pb;
        }
        bf16x8 pf0 = *(const bf16x8*)&sh[16 * w + lo][hi * 8];
        bf16x8 pf1 = *(const bf16x8*)&sh[16 * w + lo][32 + hi * 8];

        // PV: D[c][t] += V·P
        __builtin_amdgcn_s_setprio(1);
        acc0 = mfma16(*(const bf16x8*)(vc + (lo) * 64 + rc0), pf0, acc0);
        acc1 = mfma16(*(const bf16x8*)(vc + (16 + lo) * 64 + rc0), pf0, acc1);
        acc2 = mfma16(*(const bf16x8*)(vc + (32 + lo) * 64 + rc0), pf0, acc2);
        acc3 = mfma16(*(const bf16x8*)(vc + (48 + lo) * 64 + rc0), pf0, acc3);
        acc0 = mfma16(*(const bf16x8*)(vc + (lo) * 64 + rc1), pf1, acc0);
        acc1 = mfma16(*(const bf16x8*)(vc + (16 + lo) * 64 + rc1), pf1, acc1);
        acc2 = mfma16(*(const bf16x8*)(vc + (32 + lo) * 64 + rc1), pf1, acc2);
        acc3 = mfma16(*(const bf16x8*)(vc + (48 + lo) * 64 + rc1), pf1, acc3);
        __builtin_amdgcn_s_setprio(0);

        if (st < 15) {   // write-late into the other buffer (readers finished at prev barrier)
            *(bf16x8*)(kS[(st + 1) & 1] + srow * 64 + swz) = kr;
            *(bf16x8*)(vS[(st + 1) & 1] + srow * 64 + swz) = vr;
        }
        __syncthreads();   // single barrier per tile
    }

    float rl = vsc / l_run;
    {
        bf16x4 o0 = {(__bf16)(acc0[0] * rl), (__bf16)(acc0[1] * rl), (__bf16)(acc0[2] * rl), (__bf16)(acc0[3] * rl)};
        bf16x4 o1 = {(__bf16)(acc1[0] * rl), (__bf16)(acc1[1] * rl), (__bf16)(acc1[2] * rl), (__bf16)(acc1[3] * rl)};
        bf16x4 o2 = {(__bf16)(acc2[0] * rl), (__bf16)(acc2[1] * rl), (__bf16)(acc2[2] * rl), (__bf16)(acc2[3] * rl)};
        bf16x4 o3 = {(__bf16)(acc3[0] * rl), (__bf16)(acc3[1] * rl), (__bf16)(acc3[2] * rl), (__bf16)(acc3[3] * rl)};
        *(bf16x4*)&sh[16 * w + lo][0  + hi * 4] = o0;
        *(bf16x4*)&sh[16 * w + lo][16 + hi * 4] = o1;
        *(bf16x4*)&sh[16 * w + lo][32 + hi * 4] = o2;
        *(bf16x4*)&sh[16 * w + lo][48 + hi * 4] = o3;
    }
    __syncthreads();
    __bf16* ap = aT + ((size_t)b * 1024 + t0 + (tid >> 2)) * 512 + hh * 64;
    bf16x8 v0 = *(const bf16x8*)&sh[tid >> 2][(tid & 3) * 8];
    bf16x8 v1 = *(const bf16x8*)&sh[tid >> 2][32 + (tid & 3) * 8];
    *(bf16x8*)(ap + (tid & 3) * 8) = v0;
    *(bf16x8*)(ap + 32 + (tid & 3) * 8) = v1;
}

// ---------------- fallback attention (fp32 qkv, used if ws too small) ----------------
__global__ __launch_bounds__(256) void attn_mfma(const float* __restrict__ qkv,
                                                 const float* __restrict__ pmm,
                                                 __bf16* __restrict__ aT) {
    int f = blockIdx.x;
    int bh = (f & 7) * 8 + ((f >> 3) & 7);
    int tt = f >> 6;
    int b = bh >> 3, hh = bh & 7;
    int t0 = tt * 64;
    const float* qg = qkv + (size_t)(b * 1536 + hh * 192) * 1024;
    const float* kg = qg + (size_t)64 * 1024;
    const float* vg = qg + (size_t)128 * 1024;
    int tid = threadIdx.x;

    __shared__ float sred[8];
    float mn0, mx0, mn1, mx1, mn2, mx2;
    red_mm(pmm, 0, tid, sred, mn0, mx0);
    red_mm(pmm, 1, tid, sred, mn1, mx1);
    red_mm(pmm, 2, tid, sred, mn2, mx2);
    float qsc = fmaxf((mx0 - mn0) * (1.f / 255.f), 1e-8f), qzp = rintf(-mn0 / qsc);
    float ksc = fmaxf((mx1 - mn1) * (1.f / 255.f), 1e-8f), kzp = rintf(-mn1 / ksc);
    float vsc = fmaxf((mx2 - mn2) * (1.f / 255.f), 1e-8f), vzp = rintf(-mn2 / vsc);
    float inv_q = 1.f / qsc, inv_k = 1.f / ksc, inv_v = 1.f / vsc;
    float alpha = qsc * ksc * 0.125f;

    __shared__ __bf16 qT[64][72];
    __shared__ __bf16 kT[64][72];
    __shared__ __bf16 vL[64][72];
    __shared__ __bf16 pL[4][16][72];

    int l = tid & 63, w = tid >> 6;
    int lo = l & 15, hi = l >> 4;
    int c0 = (tid >> 4) * 4;
    int tl = tid & 15;

#pragma unroll
    for (int r = 0; r < 4; ++r) {
        int t = tl + 16 * r;
        float y0 = dqi(qg[(size_t)(c0 + 0) * 1024 + t0 + t], inv_q, qzp);
        float y1 = dqi(qg[(size_t)(c0 + 1) * 1024 + t0 + t], inv_q, qzp);
        float y2 = dqi(qg[(size_t)(c0 + 2) * 1024 + t0 + t], inv_q, qzp);
        float y3 = dqi(qg[(size_t)(c0 + 3) * 1024 + t0 + t], inv_q, qzp);
        bf16x4 o = {(__bf16)y0, (__bf16)y1, (__bf16)y2, (__bf16)y3};
        *(bf16x4*)&qT[t][c0] = o;
    }
    __syncthreads();
    bf16x8 qf0 = *(const bf16x8*)&qT[16 * w + lo][hi * 8];
    bf16x8 qf1 = *(const bf16x8*)&qT[16 * w + lo][32 + hi * 8];

    f32x4 acc0 = {}, acc1 = {}, acc2 = {}, acc3 = {};
    float m_run = -1e30f, l_run = 0.f;

    for (int st = 0; st < 16; ++st) {
        int s0 = st * 64;
        __syncthreads();
#pragma unroll
        for (int r = 0; r < 4; ++r) {
            int srow = tl + 16 * r;
            float y0 = dqi(kg[(size_t)(c0 + 0) * 1024 + s0 + srow], inv_k, kzp);
            float y1 = dqi(kg[(size_t)(c0 + 1) * 1024 + s0 + srow], inv_k, kzp);
            float y2 = dqi(kg[(size_t)(c0 + 2) * 1024 + s0 + srow], inv_k, kzp);
            float y3 = dqi(kg[(size_t)(c0 + 3) * 1024 + s0 + srow], inv_k, kzp);
            bf16x4 ok = {(__bf16)y0, (__bf16)y1, (__bf16)y2, (__bf16)y3};
            *(bf16x4*)&kT[srow][c0] = ok;
            int c = (tid >> 4) + 16 * r;
            float4 vv = *(const float4*)(vg + (size_t)c * 1024 + s0 + (tid & 15) * 4);
            bf16x4 ov = {(__bf16)dqi(vv.x, inv_v, vzp), (__bf16)dqi(vv.y, inv_v, vzp),
                         (__bf16)dqi(vv.z, inv_v, vzp), (__bf16)dqi(vv.w, inv_v, vzp)};
            *(bf16x4*)&vL[c][(tid & 15) * 4] = ov;
        }
        __syncthreads();

        f32x4 sf[4] = {};
#pragma unroll
        for (int sm = 0; sm < 4; ++sm)
            sf[sm] = mfma16(*(const bf16x8*)&kT[16 * sm + lo][hi * 8], qf0, sf[sm]);
#pragma unroll
        for (int sm = 0; sm < 4; ++sm)
            sf[sm] = mfma16(*(const bf16x8*)&kT[16 * sm + lo][32 + hi * 8], qf1, sf[sm]);

        float tm = -1e30f;
#pragma unroll
        for (int sm = 0; sm < 4; ++sm)
#pragma unroll
            for (int r = 0; r < 4; ++r) { sf[sm][r] *= alpha; tm = fmaxf(tm, sf[sm][r]); }
        tm = fmaxf(tm, __shfl_xor(tm, 16));
        tm = fmaxf(tm, __shfl_xor(tm, 32));
        float mnew = fmaxf(m_run, tm);
        float ts = 0.f;
#pragma unroll
        for (int sm = 0; sm < 4; ++sm)
#pragma unroll
            for (int r = 0; r < 4; ++r) {
                float p = __expf(sf[sm][r] - mnew);
                sf[sm][r] = p;
                ts += p;
            }
        ts += __shfl_xor(ts, 16);
        ts += __shfl_xor(ts, 32);
        float fr = __expf(m_run - mnew);
        l_run = l_run * fr + ts;
        m_run = mnew;
        acc0 *= fr; acc1 *= fr; acc2 *= fr; acc3 *= fr;

#pragma unroll
        for (int sm = 0; sm < 4; ++sm) {
            bf16x4 pb = {(__bf16)sf[sm][0], (__bf16)sf[sm][1], (__bf16)sf[sm][2], (__bf16)sf[sm][3]};
            *(bf16x4*)&pL[w][lo][16 * sm + hi * 4] = pb;
        }
        bf16x8 pf0 = *(const bf16x8*)&pL[w][lo][hi * 8];
        bf16x8 pf1 = *(const bf16x8*)&pL[w][lo][32 + hi * 8];
        acc0 = mfma16(*(const bf16x8*)&vL[lo][hi * 8], pf0, acc0);
        acc1 = mfma16(*(const bf16x8*)&vL[16 + lo][hi * 8], pf0, acc1);
        acc2 = mfma16(*(const bf16x8*)&vL[32 + lo][hi * 8], pf0, acc2);
        acc3 = mfma16(*(const bf16x8*)&vL[48 + lo][hi * 8], pf0, acc3);
        acc0 = mfma16(*(const bf16x8*)&vL[lo][32 + hi * 8], pf1, acc0);
        acc1 = mfma16(*(const bf16x8*)&vL[16 + lo][32 + hi * 8], pf1, acc1);
        acc2 = mfma16(*(const bf16x8*)&vL[32 + lo][32 + hi * 8], pf1, acc2);
        acc3 = mfma16(*(const bf16x8*)&vL[48 + lo][32 + hi * 8], pf1, acc3);
    }

    float rl = vsc / l_run;
    __syncthreads();
    {
        bf16x4 o0 = {(__bf16)(acc0[0] * rl), (__bf16)(acc0[1] * rl), (__bf16)(acc0[2] * rl), (__bf16)(acc0[3] * rl)};
        bf16x4 o1 = {(__bf16)(acc1[0] * rl), (__bf16)(acc1[1] * rl), (__bf16)(acc1[2] * rl), (__bf16)(acc1[3] * rl)};
        bf16x4 o2 = {(__bf16)(acc2[0] * rl), (__bf16)(acc2[1] * rl), (__bf16)(acc2[2] * rl), (__bf16)(acc2[3] * rl)};
        bf16x4 o3 = {(__bf16)(acc3[0] * rl), (__bf16)(acc3[1] * rl), (__bf16)(acc3[2] * rl), (__bf16)(acc3[3] * rl)};
        *(bf16x4*)&qT[16 * w + lo][0  + hi * 4] = o0;
        *(bf16x4*)&qT[16 * w + lo][16 + hi * 4] = o1;
        *(bf16x4*)&qT[16 * w + lo][32 + hi * 4] = o2;
        *(bf16x4*)&qT[16 * w + lo][48 + hi * 4] = o3;
    }
    __syncthreads();
    __bf16* ap = aT + ((size_t)b * 1024 + t0 + (tid >> 2)) * 512 + hh * 64;
    bf16x8 v0 = *(const bf16x8*)&qT[tid >> 2][(tid & 3) * 8];
    bf16x8 v1 = *(const bf16x8*)&qT[tid >> 2][32 + (tid & 3) * 8];
    *(bf16x8*)(ap + (tid & 3) * 8) = v0;
    *(bf16x8*)(ap + 32 + (tid & 3) * 8) = v1;
}

extern "C" void kernel_launch(void* const* d_in, const int* in_sizes, int n_in,
                              void* d_out, int out_size, void* d_ws, size_t ws_size,
                              hipStream_t stream) {
    const float* x      = (const float*)d_in[0];
    const float* gn_w   = (const float*)d_in[1];
    const float* gn_b   = (const float*)d_in[2];
    const float* qkv_w  = (const float*)d_in[3];
    const float* qkv_b  = (const float*)d_in[4];
    const float* proj_w = (const float*)d_in[5];
    const float* proj_b = (const float*)d_in[6];
    char* ws = (char*)d_ws;
    float*    qkv = (float*)(ws + QKV_OFF);
    __bf16*   hT  = (__bf16*)(ws + HT_OFF);   // hT, later reused as aT
    __bf16*   wq  = (__bf16*)(ws + WQ_OFF);
    __bf16*   wp  = (__bf16*)(ws + WP_OFF);
    float*    pmm = (float*)(ws + MM_OFF);    // 3 x 256 x {mn,mx} partials
    float*    gst = (float*)(ws + GST_OFF);   // mean[256], rstd[256]
    __bf16*   ki  = (__bf16*)(ws + KI_OFF);
    __bf16*   vi  = (__bf16*)(ws + VI_OFF);
    float* out = (float*)d_out;

    gnstats<<<1280, 256, 0, stream>>>(x, qkv_w, wq, proj_w, wp, gst);
    gnapply<<<256, 256, 0, stream>>>(x, gn_w, gn_b, gst, hT);
    mgemm5<128, 12, true, false><<<768, 256, 0, stream>>>(wq, hT, qkv_b, nullptr, qkv, 1536, pmm);
    if (ws_size >= NEED_NEW) {
        quant_kv<<<1024, 256, 0, stream>>>(qkv, pmm, ki, vi);
        attn5<<<512, 512, 0, stream>>>(qkv, ki, vi, pmm, hT);
    } else {
        attn_mfma<<<1024, 256, 0, stream>>>(qkv, pmm, hT);
    }
    mgemm5<64, 8, false, true><<<512, 256, 0, stream>>>(wp, hT, proj_b, x, out, 512, nullptr);
}

// Round 15
// 86.886 us; speedup vs baseline: 1.1574x; 1.0808x over previous
//
#include <hip/hip_runtime.h>

typedef __attribute__((ext_vector_type(8))) __bf16 bf16x8;
typedef __attribute__((ext_vector_type(4))) __bf16 bf16x4;
typedef __attribute__((ext_vector_type(4))) float  f32x4;

// Problem: x (8,512,32,32) fp32 -> B=8, C=512, T=1024; 32 groups; 8 heads (ch=64)

// ws layout (bytes)
static constexpr size_t QKV_OFF = 0;                     // bf16 (8,1536,1024) 24MB
static constexpr size_t HT_OFF  = 50331648;              // bf16 (8,1024,512) 8MB: hT then aT
static constexpr size_t WQ_OFF  = HT_OFF + 8388608;      // bf16 (1536,512)
static constexpr size_t WP_OFF  = WQ_OFF + 1572864;      // bf16 (512,512)
static constexpr size_t MM_OFF  = WP_OFF + 524288;       // pmm: 3 x 512 slots x {mn,mx} = 12288B
static constexpr size_t GST_OFF = MM_OFF + 12288;        // mean[256], rstd[256] f32
static constexpr size_t KI_OFF  = MM_OFF + 16384;        // bf16 (64,1024,64) 8MB
static constexpr size_t VI_OFF  = KI_OFF + 8388608;      // bf16 (64,64,1024) 8MB
static constexpr size_t NEED_NEW = VI_OFF + 8388608;

// integer-valued dequant core: clip(rint(x/s)+zp,0,255)-zp == clip(rint(x/s), -zp, 255-zp)
__device__ __forceinline__ float dqi(float x, float inv_s, float zp) {
    float y = rintf(x * inv_s);
    return fminf(fmaxf(y, -zp), 255.0f - zp);
}
__device__ __forceinline__ f32x4 mfma16(bf16x8 a, bf16x8 b, f32x4 c) {
    return __builtin_amdgcn_mfma_f32_16x16x32_bf16(a, b, c, 0, 0, 0);
}
__device__ __forceinline__ float exp2i(float x) {  // raw v_exp_f32 (2^x)
    float r;
    asm("v_exp_f32 %0, %1" : "=v"(r) : "v"(x));
    return r;
}
__device__ __forceinline__ void glds16(const __bf16* g, __bf16* l) {
    __builtin_amdgcn_global_load_lds((const __attribute__((address_space(1))) void*)g,
                                     (__attribute__((address_space(3))) void*)l, 16, 0, 0);
}
template <int N> __device__ __forceinline__ void waitv() {
    asm volatile("s_waitcnt vmcnt(%0)" :: "n"(N) : "memory");
}
__device__ __forceinline__ void bar_raw() {
    asm volatile("s_barrier" ::: "memory");
}

// reduce pmm[id][512][2] partials -> (mn, mx). 256-thread version (2 slots/thread).
__device__ __forceinline__ void red_mm(const float* __restrict__ pmm, int id, int tid,
                                       float* sred, float& mn_out, float& mx_out) {
    const float* p = pmm + id * 1024;
    float mn = fminf(p[tid * 2],     p[(tid + 256) * 2]);
    float mx = fmaxf(p[tid * 2 + 1], p[(tid + 256) * 2 + 1]);
#pragma unroll
    for (int m = 1; m < 64; m <<= 1) {
        mn = fminf(mn, __shfl_xor(mn, m));
        mx = fmaxf(mx, __shfl_xor(mx, m));
    }
    if ((tid & 63) == 0) { sred[(tid >> 6) * 2] = mn; sred[(tid >> 6) * 2 + 1] = mx; }
    __syncthreads();
    mn = fminf(fminf(sred[0], sred[2]), fminf(sred[4], sred[6]));
    mx = fmaxf(fmaxf(sred[1], sred[3]), fmaxf(sred[5], sred[7]));
    __syncthreads();
    mn_out = fminf(mn, 0.0f);
    mx_out = fmaxf(mx, 0.0f);
}

// 512-thread version (1 slot/thread)
__device__ __forceinline__ void red_mm8(const float* __restrict__ pmm, int id, int tid,
                                        float* sred, float& mn_out, float& mx_out) {
    const float* p = pmm + id * 1024;
    float mn = p[tid * 2];
    float mx = p[tid * 2 + 1];
#pragma unroll
    for (int m = 1; m < 64; m <<= 1) {
        mn = fminf(mn, __shfl_xor(mn, m));
        mx = fmaxf(mx, __shfl_xor(mx, m));
    }
    if ((tid & 63) == 0) { sred[(tid >> 6) * 2] = mn; sred[(tid >> 6) * 2 + 1] = mx; }
    __syncthreads();
    float a = fminf(fminf(sred[0], sred[2]), fminf(sred[4], sred[6]));
    float b = fminf(fminf(sred[8], sred[10]), fminf(sred[12], sred[14]));
    mn = fminf(a, b);
    a = fmaxf(fmaxf(sred[1], sred[3]), fmaxf(sred[5], sred[7]));
    b = fmaxf(fmaxf(sred[9], sred[11]), fmaxf(sred[13], sred[15]));
    mx = fmaxf(a, b);
    __syncthreads();
    mn_out = fminf(mn, 0.0f);
    mx_out = fmaxf(mx, 0.0f);
}

// ---------------- gnstats: weight fp32->bf16 convert + per-(b,g) mean/rstd ----------------
__global__ __launch_bounds__(256) void gnstats(const float* __restrict__ x,
                                               const float* __restrict__ qw,
                                               __bf16* __restrict__ wq,
                                               const float* __restrict__ pw,
                                               __bf16* __restrict__ wp,
                                               float* __restrict__ gst) {
    int bid = blockIdx.x, tid = threadIdx.x;
    if (bid < 1024) {
        if (bid < 768) {
            int i = bid * 256 + tid;
            float4 v = ((const float4*)qw)[i];
            bf16x4 o = {(__bf16)v.x, (__bf16)v.y, (__bf16)v.z, (__bf16)v.w};
            ((bf16x4*)wq)[i] = o;
        } else {
            int i = (bid - 768) * 256 + tid;
            float4 v = ((const float4*)pw)[i];
            bf16x4 o = {(__bf16)v.x, (__bf16)v.y, (__bf16)v.z, (__bf16)v.w};
            ((bf16x4*)wp)[i] = o;
        }
        return;
    }
    int blk = bid - 1024;
    int b = blk >> 5, g = blk & 31;
    const float* xp = x + (size_t)(b * 512 + g * 16) * 1024;

    float sum = 0.f, ss = 0.f;
#pragma unroll
    for (int i = 0; i < 16; ++i) {
        float4 v = *(const float4*)(xp + (size_t)i * 1024 + tid * 4);
        sum += v.x + v.y + v.z + v.w;
        ss  += v.x * v.x + v.y * v.y + v.z * v.z + v.w * v.w;
    }
#pragma unroll
    for (int m = 1; m < 64; m <<= 1) {
        sum += __shfl_xor(sum, m);
        ss  += __shfl_xor(ss, m);
    }
    __shared__ float s1[4], s2[4];
    int wid = tid >> 6;
    if ((tid & 63) == 0) { s1[wid] = sum; s2[wid] = ss; }
    __syncthreads();
    if (tid == 0) {
        sum = s1[0] + s1[1] + s1[2] + s1[3];
        ss  = s2[0] + s2[1] + s2[2] + s2[3];
        float mean = sum * (1.0f / 16384.0f);
        float var  = ss * (1.0f / 16384.0f) - mean * mean;
        gst[blk]       = mean;
        gst[256 + blk] = rsqrtf(var + 1e-5f);
    }
}

// ---------------- gnapply: t-major normalize + transpose, coalesced both sides ----------------
__global__ __launch_bounds__(256) void gnapply(const float* __restrict__ x,
                                               const float* __restrict__ w,
                                               const float* __restrict__ bv,
                                               const float* __restrict__ gst,
                                               __bf16* __restrict__ hT) {
    int f = blockIdx.x;
    int b = f & 7, ts = f >> 3;
    int t0 = ts * 32;
    int tid = threadIdx.x;

    __shared__ __bf16 sH[32][520];
    int cl = tid >> 3;
    int tl = (tid & 7) * 4;

#pragma unroll
    for (int ci = 0; ci < 16; ++ci) {
        int c = ci * 32 + cl;
        int g = c >> 4;
        float mean = gst[b * 32 + g];
        float rstd = gst[256 + b * 32 + g];
        float wc = w[c] * rstd, bc = bv[c];
        float4 v = *(const float4*)(x + ((size_t)(b * 512 + c)) * 1024 + t0 + tl);
        sH[tl + 0][c] = (__bf16)((v.x - mean) * wc + bc);
        sH[tl + 1][c] = (__bf16)((v.y - mean) * wc + bc);
        sH[tl + 2][c] = (__bf16)((v.z - mean) * wc + bc);
        sH[tl + 3][c] = (__bf16)((v.w - mean) * wc + bc);
    }
    __syncthreads();
    int lane = tid & 63, wv = tid >> 6;
#pragma unroll
    for (int it = 0; it < 8; ++it) {
        int row = it * 4 + wv;
        bf16x8 o = *(const bf16x8*)&sH[row][lane * 8];
        *(bf16x8*)(hT + ((size_t)(b * 1024 + t0 + row)) * 512 + lane * 8) = o;
    }
}

// ---------------- MFMA GEMM v6: BK=64 swizzle + counted-vmcnt dbuf; per-64-row minmax; bf16 out opt ----------------
template <int MTILE, int MOT, bool MINMAX, bool RESID, bool OUT16>
__global__ __launch_bounds__(256, 2) void mgemm6(const __bf16* __restrict__ A,   // [M][512]
                                                 const __bf16* __restrict__ Bt,  // [8][1024][512]
                                                 const float* __restrict__ bias,
                                                 const float* __restrict__ resid,
                                                 void* __restrict__ outv,
                                                 int M, float* __restrict__ pmm) {
    constexpr int NF  = (MTILE == 128) ? 4 : 2;
    constexpr int ASZ = MTILE * 64;
    constexpr int BSZ = 128 * 64;
    constexpr int LA  = MTILE / 32;
    constexpr int L   = LA + 4;
    constexpr int STG = 2 * (ASZ + BSZ) * 2;
    constexpr int CSB = 64 * 132 * 4;
    __shared__ __attribute__((aligned(16))) char smem_raw[(STG > CSB) ? STG : CSB];
    __bf16* sA0 = (__bf16*)smem_raw;
    __bf16* sA1 = sA0 + ASZ;
    __bf16* sB0 = sA1 + ASZ;
    __bf16* sB1 = sB0 + BSZ;
    __shared__ float smn[4], smx[4];

    int tid = threadIdx.x;
    int l = tid & 63, w = tid >> 6;
    int lo = l & 15, hi = l >> 4;

    int f = blockIdx.x;
    constexpr int NWG = MOT * 64;
    int wg = (f & 7) * (NWG / 8) + (f >> 3);
    int mo = wg % MOT, nb = wg / MOT;
    int nt = nb & 7, b = nb >> 3;

    const __bf16* Ap = A + (size_t)mo * MTILE * 512;
    const __bf16* Bp = Bt + ((size_t)b * 1024 + (size_t)nt * 128) * 512;
    int m0 = (MTILE == 128) ? (w >> 1) * 64 : 0;
    int n0 = (MTILE == 128) ? (w & 1) * 64 : w * 32;
    f32x4 acc[4][NF] = {};
    int scd = tid & 7;

    auto STAGE = [&](__bf16* dA, __bf16* dB, int k0) {
#pragma unroll
        for (int p = 0; p < LA; ++p) {
            int lin = p * 2048 + tid * 8;
            int row = lin >> 6;
            glds16(Ap + (size_t)row * 512 + k0 + ((scd ^ (row & 7)) << 3), dA + lin);
        }
#pragma unroll
        for (int p = 0; p < 4; ++p) {
            int lin = p * 2048 + tid * 8;
            int row = lin >> 6;
            glds16(Bp + (size_t)row * 512 + k0 + ((scd ^ (row & 7)) << 3), dB + lin);
        }
    };
    auto COMPUTE = [&](const __bf16* cA, const __bf16* cB) {
#pragma unroll
        for (int kk = 0; kk < 2; ++kk) {
            int rch = ((kk * 4 + hi) ^ (lo & 7)) << 3;
            bf16x8 af[4], bfr[NF];
#pragma unroll
            for (int i = 0; i < 4; ++i) af[i] = *(const bf16x8*)&cA[(m0 + 16 * i + lo) * 64 + rch];
#pragma unroll
            for (int j = 0; j < NF; ++j) bfr[j] = *(const bf16x8*)&cB[(n0 + 16 * j + lo) * 64 + rch];
#pragma unroll
            for (int i = 0; i < 4; ++i)
#pragma unroll
                for (int j = 0; j < NF; ++j) acc[i][j] = mfma16(af[i], bfr[j], acc[i][j]);
        }
    };

    STAGE(sA0, sB0, 0);
#pragma unroll
    for (int kp = 0; kp < 8; kp += 2) {
        if (kp + 1 < 8) { STAGE(sA1, sB1, (kp + 1) * 64); waitv<L>(); } else { waitv<0>(); }
        bar_raw();
        COMPUTE(sA0, sB0);
        bar_raw();
        if (kp + 2 < 8) { STAGE(sA0, sB0, (kp + 2) * 64); waitv<L>(); } else { waitv<0>(); }
        bar_raw();
        COMPUTE(sA1, sB1);
        bar_raw();
    }

    float* cs = (float*)smem_raw;
    constexpr int NH = (MTILE == 128) ? 2 : 1;
#pragma unroll
    for (int h = 0; h < NH; ++h) {
        float mn = 1e30f, mx = -1e30f;
        __syncthreads();
        if (MTILE == 64 || (w >> 1) == h) {
#pragma unroll
            for (int i = 0; i < 4; ++i)
#pragma unroll
                for (int r = 0; r < 4; ++r) {
                    int rl = 16 * i + hi * 4 + r;
                    float bi = bias[mo * MTILE + h * 64 + rl];
#pragma unroll
                    for (int j = 0; j < NF; ++j)
                        cs[rl * 132 + n0 + 16 * j + lo] = acc[i][j][r] + bi;
                }
        }
        __syncthreads();
#pragma unroll
        for (int it = 0; it < 8; ++it) {
            int lin = it * 256 + tid;
            int rr = lin >> 5, cc = (lin & 31) << 2;
            float4 v = *(const float4*)&cs[rr * 132 + cc];
            if (MINMAX) {
                mn = fminf(mn, fminf(fminf(v.x, v.y), fminf(v.z, v.w)));
                mx = fmaxf(mx, fmaxf(fmaxf(v.x, v.y), fmaxf(v.z, v.w)));
            }
            int grow = mo * MTILE + h * 64 + rr;
            size_t gaddr = ((size_t)b * M + grow) * 1024 + nt * 128 + cc;
            if (RESID) {
                float4 rv = *(const float4*)&resid[gaddr];
                v.x += rv.x; v.y += rv.y; v.z += rv.z; v.w += rv.w;
            }
            if (OUT16) {
                bf16x4 o16 = {(__bf16)v.x, (__bf16)v.y, (__bf16)v.z, (__bf16)v.w};
                *(bf16x4*)&(((__bf16*)outv)[gaddr]) = o16;
            } else {
                *(float4*)&(((float*)outv)[gaddr]) = v;
            }
        }

        if (MINMAX) {
            // per-64-row-half reduction: this half belongs to tensor id=(2mo+h)%3, head (2mo+h)/3
#pragma unroll
            for (int msk = 1; msk < 64; msk <<= 1) {
                mn = fminf(mn, __shfl_xor(mn, msk));
                mx = fmaxf(mx, __shfl_xor(mx, msk));
            }
            if (l == 0) { smn[w] = mn; smx[w] = mx; }
            __syncthreads();
            if (tid == 0) {
                mn = fminf(fminf(smn[0], smn[1]), fminf(smn[2], smn[3]));
                mx = fmaxf(fmaxf(smx[0], smx[1]), fmaxf(smx[2], smx[3]));
                int o = 2 * mo + h;
                int id = o % 3;                     // q/k/v per the head-interleaved layout
                int slot = (o / 3) * 64 + nb;       // 0..511, unique per (id, block-half)
                pmm[id * 1024 + slot * 2]     = mn;
                pmm[id * 1024 + slot * 2 + 1] = mx;
            }
            __syncthreads();   // smn/smx reuse guard for next half
        }
    }
}

// ---------------- quant K/V pass, XCD-aligned; bf16 qkv input ----------------
__global__ __launch_bounds__(256) void quant_kv(const __bf16* __restrict__ qkv,
                                                const float* __restrict__ pmm,
                                                __bf16* __restrict__ ki,
                                                __bf16* __restrict__ vi) {
    int f = blockIdx.x;
    int b = f & 7;
    int r2 = f >> 3;
    int hh = r2 & 7, tt = r2 >> 3;
    int bh = b * 8 + hh;
    int t0 = tt * 64;
    const __bf16* kg = qkv + ((size_t)(b * 1536 + hh * 192) + 64) * 1024;
    const __bf16* vg = kg + 65536;
    int tid = threadIdx.x;

    __shared__ float sred[8];
    float mn1, mx1, mn2, mx2;
    red_mm(pmm, 1, tid, sred, mn1, mx1);
    red_mm(pmm, 2, tid, sred, mn2, mx2);
    float ksc = fmaxf((mx1 - mn1) * (1.f / 255.f), 1e-8f), kzp = rintf(-mn1 / ksc);
    float vsc = fmaxf((mx2 - mn2) * (1.f / 255.f), 1e-8f), vzp = rintf(-mn2 / vsc);
    float inv_k = 1.f / ksc, inv_v = 1.f / vsc;

    __shared__ __bf16 sT[64][68];
    int cr = tid >> 4, t4 = tid & 15;
    int s = tid >> 2, c0 = (tid & 3) * 16;

    __bf16* vd = vi + (size_t)bh * 65536;
#pragma unroll
    for (int r = 0; r < 4; ++r) {
        int c = 16 * r + cr;
        bf16x4 v = *(const bf16x4*)(vg + (size_t)c * 1024 + t0 + t4 * 4);
        bf16x4 o = {(__bf16)dqi((float)v[0], inv_v, vzp), (__bf16)dqi((float)v[1], inv_v, vzp),
                    (__bf16)dqi((float)v[2], inv_v, vzp), (__bf16)dqi((float)v[3], inv_v, vzp)};
        *(bf16x4*)(vd + (size_t)c * 1024 + t0 + t4 * 4) = o;
    }

#pragma unroll
    for (int r = 0; r < 4; ++r) {
        int c = 16 * r + cr;
        bf16x4 v = *(const bf16x4*)(kg + (size_t)c * 1024 + t0 + t4 * 4);
        sT[t4 * 4 + 0][c] = (__bf16)dqi((float)v[0], inv_k, kzp);
        sT[t4 * 4 + 1][c] = (__bf16)dqi((float)v[1], inv_k, kzp);
        sT[t4 * 4 + 2][c] = (__bf16)dqi((float)v[2], inv_k, kzp);
        sT[t4 * 4 + 3][c] = (__bf16)dqi((float)v[3], inv_k, kzp);
    }
    __syncthreads();
    bf16x8 a0 = *(const bf16x8*)&sT[s][c0];
    bf16x8 a1 = *(const bf16x8*)&sT[s][c0 + 8];
    __bf16* kd = ki + ((size_t)bh * 1024 + t0 + s) * 64 + c0;
    *(bf16x8*)kd = a0;
    *(bf16x8*)(kd + 8) = a1;
}

// ---------------- attention: QBLK=128, 8 waves, dbuf K/V, 1 barrier/tile ----------------
__global__ __launch_bounds__(512, 4) void attn5(const __bf16* __restrict__ qkv,
                                                const __bf16* __restrict__ ki,
                                                const __bf16* __restrict__ vi,
                                                const float* __restrict__ pmm,
                                                __bf16* __restrict__ aT) {
    int f = blockIdx.x;
    int bh = (f & 7) * 8 + ((f >> 3) & 7);  // batch b = f&7 -> XCD b
    int tt = f >> 6;                        // 0..7
    int b = bh >> 3, hh = bh & 7;
    int t0 = tt * 128;
    const __bf16* qg = qkv + (size_t)(b * 1536 + hh * 192) * 1024;
    const __bf16* kb = ki + (size_t)bh * 65536;
    const __bf16* vb = vi + (size_t)bh * 65536;
    int tid = threadIdx.x;

    __shared__ float sred[16];
    float mn0, mx0, mn1, mx1, mn2, mx2;
    red_mm8(pmm, 0, tid, sred, mn0, mx0);
    red_mm8(pmm, 1, tid, sred, mn1, mx1);
    red_mm8(pmm, 2, tid, sred, mn2, mx2);
    float qsc = fmaxf((mx0 - mn0) * (1.f / 255.f), 1e-8f), qzp = rintf(-mn0 / qsc);
    float ksc = fmaxf((mx1 - mn1) * (1.f / 255.f), 1e-8f);
    float vsc = fmaxf((mx2 - mn2) * (1.f / 255.f), 1e-8f);
    float inv_q = 1.f / qsc;
    float alpha2 = qsc * ksc * 0.125f * 1.4426950408889634f;  // alpha * log2(e)
    float thr = 11.5415603f / alpha2;                          // 8 nats in raw-score units

    __shared__ __bf16 sh[128][72];   // q stage -> per-wave P -> output stage
    __shared__ __bf16 kS[2][4096];   // K tile (s,c), chunk-swizzled, double-buffered
    __shared__ __bf16 vS[2][4096];   // V tile (c,s), chunk-swizzled, double-buffered
    int l = tid & 63, w = tid >> 6;
    int lo = l & 15, hi = l >> 4;

    // staging geometry: thread -> row (0..63), one 16B chunk each for K and V
    int srow = tid >> 3, sc = tid & 7;
    int swz = (sc ^ (srow & 7)) << 3;
    const __bf16* kROW = kb + (size_t)srow * 64;          // + st*4096
    const __bf16* vROW = vb + (size_t)srow * 1024;        // + st*64
    int lx = lo & 7;
    int rc0 = (hi ^ lx) << 3;
    int rc1 = ((4 + hi) ^ lx) << 3;

    // issue tile-0 loads early; hide under q staging
    bf16x8 kr = *(const bf16x8*)(kROW + sc * 8);
    bf16x8 vr = *(const bf16x8*)(vROW + sc * 8);

    // inline q stage: transpose + dequant to integer-valued bf16 (128 t x 64 c)
    {
        int c0 = (tid >> 5) * 4;     // 0..60
        int tl = tid & 31;
#pragma unroll
        for (int r = 0; r < 4; ++r) {
            int t = tl + 32 * r;
            float y0 = dqi((float)qg[(size_t)(c0 + 0) * 1024 + t0 + t], inv_q, qzp);
            float y1 = dqi((float)qg[(size_t)(c0 + 1) * 1024 + t0 + t], inv_q, qzp);
            float y2 = dqi((float)qg[(size_t)(c0 + 2) * 1024 + t0 + t], inv_q, qzp);
            float y3 = dqi((float)qg[(size_t)(c0 + 3) * 1024 + t0 + t], inv_q, qzp);
            bf16x4 o = {(__bf16)y0, (__bf16)y1, (__bf16)y2, (__bf16)y3};
            *(bf16x4*)&sh[t][c0] = o;
        }
    }
    __syncthreads();
    bf16x8 qf0 = *(const bf16x8*)&sh[16 * w + lo][hi * 8];
    bf16x8 qf1 = *(const bf16x8*)&sh[16 * w + lo][32 + hi * 8];
    // stage tile 0 (waits vmcnt via data dep)
    *(bf16x8*)(kS[0] + srow * 64 + swz) = kr;
    *(bf16x8*)(vS[0] + srow * 64 + swz) = vr;
    __syncthreads();   // q reads done + tile 0 staged

    f32x4 acc0 = {}, acc1 = {}, acc2 = {}, acc3 = {};
    float m_run = -1e30f, l_run = 0.f;

    for (int st = 0; st < 16; ++st) {
        const __bf16* kc = kS[st & 1];
        const __bf16* vc = vS[st & 1];
        if (st < 15) {   // T14: issue next-tile loads before compute
            kr = *(const bf16x8*)(kROW + (st + 1) * 4096 + sc * 8);
            vr = *(const bf16x8*)(vROW + (st + 1) * 64 + sc * 8);
        }

        // scores: D[s][t] = K·Q (raw integer dot products)
        f32x4 sf[4] = {};
        __builtin_amdgcn_s_setprio(1);
#pragma unroll
        for (int sm = 0; sm < 4; ++sm)
            sf[sm] = mfma16(*(const bf16x8*)(kc + (16 * sm + lo) * 64 + rc0), qf0, sf[sm]);
#pragma unroll
        for (int sm = 0; sm < 4; ++sm)
            sf[sm] = mfma16(*(const bf16x8*)(kc + (16 * sm + lo) * 64 + rc1), qf1, sf[sm]);
        __builtin_amdgcn_s_setprio(0);

        // online softmax in exp2 space (t = lane-local)
        float tm = -1e30f;
#pragma unroll
        for (int sm = 0; sm < 4; ++sm) {
            float a = fmaxf(sf[sm][0], sf[sm][1]);
            float c = fmaxf(sf[sm][2], sf[sm][3]);
            tm = fmaxf(tm, fmaxf(a, c));
        }
        tm = fmaxf(tm, __shfl_xor(tm, 16));
        tm = fmaxf(tm, __shfl_xor(tm, 32));
        if (!__all(tm <= m_run + thr)) {   // defer-max
            float mnew = fmaxf(m_run, tm);
            float fr = exp2i(alpha2 * (m_run - mnew));
            acc0 *= fr; acc1 *= fr; acc2 *= fr; acc3 *= fr;
            l_run *= fr;
            m_run = mnew;
        }
        float cc = -alpha2 * m_run;
        float ts = 0.f;
#pragma unroll
        for (int sm = 0; sm < 4; ++sm)
#pragma unroll
            for (int r = 0; r < 4; ++r) {
                float p = exp2i(fmaf(sf[sm][r], alpha2, cc));
                sf[sm][r] = p;
                ts += p;
            }
        ts += __shfl_xor(ts, 16);
        ts += __shfl_xor(ts, 32);
        l_run += ts;

        // P -> LDS (wave-private rows)
#pragma unroll
        for (int sm = 0; sm < 4; ++sm) {
            bf16x4 pb = {(__bf16)sf[sm][0], (__bf16)sf[sm][1], (__bf16)sf[sm][2], (__bf16)sf[sm][3]};
            *(bf16x4*)&sh[16 * w + lo][16 * sm + hi * 4] = pb;
        }
        bf16x8 pf0 = *(const bf16x8*)&sh[16 * w + lo][hi * 8];
        bf16x8 pf1 = *(const bf16x8*)&sh[16 * w + lo][32 + hi * 8];

        // PV: D[c][t] += V·P
        __builtin_amdgcn_s_setprio(1);
        acc0 = mfma16(*(const bf16x8*)(vc + (lo) * 64 + rc0), pf0, acc0);
        acc1 = mfma16(*(const bf16x8*)(vc + (16 + lo) * 64 + rc0), pf0, acc1);
        acc2 = mfma16(*(const bf16x8*)(vc + (32 + lo) * 64 + rc0), pf0, acc2);
        acc3 = mfma16(*(const bf16x8*)(vc + (48 + lo) * 64 + rc0), pf0, acc3);
        acc0 = mfma16(*(const bf16x8*)(vc + (lo) * 64 + rc1), pf1, acc0);
        acc1 = mfma16(*(const bf16x8*)(vc + (16 + lo) * 64 + rc1), pf1, acc1);
        acc2 = mfma16(*(const bf16x8*)(vc + (32 + lo) * 64 + rc1), pf1, acc2);
        acc3 = mfma16(*(const bf16x8*)(vc + (48 + lo) * 64 + rc1), pf1, acc3);
        __builtin_amdgcn_s_setprio(0);

        if (st < 15) {   // write-late into the other buffer (readers finished at prev barrier)
            *(bf16x8*)(kS[(st + 1) & 1] + srow * 64 + swz) = kr;
            *(bf16x8*)(vS[(st + 1) & 1] + srow * 64 + swz) = vr;
        }
        __syncthreads();   // single barrier per tile
    }

    float rl = vsc / l_run;
    {
        bf16x4 o0 = {(__bf16)(acc0[0] * rl), (__bf16)(acc0[1] * rl), (__bf16)(acc0[2] * rl), (__bf16)(acc0[3] * rl)};
        bf16x4 o1 = {(__bf16)(acc1[0] * rl), (__bf16)(acc1[1] * rl), (__bf16)(acc1[2] * rl), (__bf16)(acc1[3] * rl)};
        bf16x4 o2 = {(__bf16)(acc2[0] * rl), (__bf16)(acc2[1] * rl), (__bf16)(acc2[2] * rl), (__bf16)(acc2[3] * rl)};
        bf16x4 o3 = {(__bf16)(acc3[0] * rl), (__bf16)(acc3[1] * rl), (__bf16)(acc3[2] * rl), (__bf16)(acc3[3] * rl)};
        *(bf16x4*)&sh[16 * w + lo][0  + hi * 4] = o0;
        *(bf16x4*)&sh[16 * w + lo][16 + hi * 4] = o1;
        *(bf16x4*)&sh[16 * w + lo][32 + hi * 4] = o2;
        *(bf16x4*)&sh[16 * w + lo][48 + hi * 4] = o3;
    }
    __syncthreads();
    __bf16* ap = aT + ((size_t)b * 1024 + t0 + (tid >> 2)) * 512 + hh * 64;
    bf16x8 v0 = *(const bf16x8*)&sh[tid >> 2][(tid & 3) * 8];
    bf16x8 v1 = *(const bf16x8*)&sh[tid >> 2][32 + (tid & 3) * 8];
    *(bf16x8*)(ap + (tid & 3) * 8) = v0;
    *(bf16x8*)(ap + 32 + (tid & 3) * 8) = v1;
}

// ---------------- fallback attention (bf16 qkv, used if ws too small) ----------------
__global__ __launch_bounds__(256) void attn_mfma(const __bf16* __restrict__ qkv,
                                                 const float* __restrict__ pmm,
                                                 __bf16* __restrict__ aT) {
    int f = blockIdx.x;
    int bh = (f & 7) * 8 + ((f >> 3) & 7);
    int tt = f >> 6;
    int b = bh >> 3, hh = bh & 7;
    int t0 = tt * 64;
    const __bf16* qg = qkv + (size_t)(b * 1536 + hh * 192) * 1024;
    const __bf16* kg = qg + (size_t)64 * 1024;
    const __bf16* vg = qg + (size_t)128 * 1024;
    int tid = threadIdx.x;

    __shared__ float sred[8];
    float mn0, mx0, mn1, mx1, mn2, mx2;
    red_mm(pmm, 0, tid, sred, mn0, mx0);
    red_mm(pmm, 1, tid, sred, mn1, mx1);
    red_mm(pmm, 2, tid, sred, mn2, mx2);
    float qsc = fmaxf((mx0 - mn0) * (1.f / 255.f), 1e-8f), qzp = rintf(-mn0 / qsc);
    float ksc = fmaxf((mx1 - mn1) * (1.f / 255.f), 1e-8f), kzp = rintf(-mn1 / ksc);
    float vsc = fmaxf((mx2 - mn2) * (1.f / 255.f), 1e-8f), vzp = rintf(-mn2 / vsc);
    float inv_q = 1.f / qsc, inv_k = 1.f / ksc, inv_v = 1.f / vsc;
    float alpha = qsc * ksc * 0.125f;

    __shared__ __bf16 qT[64][72];
    __shared__ __bf16 kT[64][72];
    __shared__ __bf16 vL[64][72];
    __shared__ __bf16 pL[4][16][72];

    int l = tid & 63, w = tid >> 6;
    int lo = l & 15, hi = l >> 4;
    int c0 = (tid >> 4) * 4;
    int tl = tid & 15;

#pragma unroll
    for (int r = 0; r < 4; ++r) {
        int t = tl + 16 * r;
        float y0 = dqi((float)qg[(size_t)(c0 + 0) * 1024 + t0 + t], inv_q, qzp);
        float y1 = dqi((float)qg[(size_t)(c0 + 1) * 1024 + t0 + t], inv_q, qzp);
        float y2 = dqi((float)qg[(size_t)(c0 + 2) * 1024 + t0 + t], inv_q, qzp);
        float y3 = dqi((float)qg[(size_t)(c0 + 3) * 1024 + t0 + t], inv_q, qzp);
        bf16x4 o = {(__bf16)y0, (__bf16)y1, (__bf16)y2, (__bf16)y3};
        *(bf16x4*)&qT[t][c0] = o;
    }
    __syncthreads();
    bf16x8 qf0 = *(const bf16x8*)&qT[16 * w + lo][hi * 8];
    bf16x8 qf1 = *(const bf16x8*)&qT[16 * w + lo][32 + hi * 8];

    f32x4 acc0 = {}, acc1 = {}, acc2 = {}, acc3 = {};
    float m_run = -1e30f, l_run = 0.f;

    for (int st = 0; st < 16; ++st) {
        int s0 = st * 64;
        __syncthreads();
#pragma unroll
        for (int r = 0; r < 4; ++r) {
            int srow = tl + 16 * r;
            float y0 = dqi((float)kg[(size_t)(c0 + 0) * 1024 + s0 + srow], inv_k, kzp);
            float y1 = dqi((float)kg[(size_t)(c0 + 1) * 1024 + s0 + srow], inv_k, kzp);
            float y2 = dqi((float)kg[(size_t)(c0 + 2) * 1024 + s0 + srow], inv_k, kzp);
            float y3 = dqi((float)kg[(size_t)(c0 + 3) * 1024 + s0 + srow], inv_k, kzp);
            bf16x4 ok = {(__bf16)y0, (__bf16)y1, (__bf16)y2, (__bf16)y3};
            *(bf16x4*)&kT[srow][c0] = ok;
            int c = (tid >> 4) + 16 * r;
            bf16x4 vv = *(const bf16x4*)(vg + (size_t)c * 1024 + s0 + (tid & 15) * 4);
            bf16x4 ov = {(__bf16)dqi((float)vv[0], inv_v, vzp), (__bf16)dqi((float)vv[1], inv_v, vzp),
                         (__bf16)dqi((float)vv[2], inv_v, vzp), (__bf16)dqi((float)vv[3], inv_v, vzp)};
            *(bf16x4*)&vL[c][(tid & 15) * 4] = ov;
        }
        __syncthreads();

        f32x4 sf[4] = {};
#pragma unroll
        for (int sm = 0; sm < 4; ++sm)
            sf[sm] = mfma16(*(const bf16x8*)&kT[16 * sm + lo][hi * 8], qf0, sf[sm]);
#pragma unroll
        for (int sm = 0; sm < 4; ++sm)
            sf[sm] = mfma16(*(const bf16x8*)&kT[16 * sm + lo][32 + hi * 8], qf1, sf[sm]);

        float tm = -1e30f;
#pragma unroll
        for (int sm = 0; sm < 4; ++sm)
#pragma unroll
            for (int r = 0; r < 4; ++r) { sf[sm][r] *= alpha; tm = fmaxf(tm, sf[sm][r]); }
        tm = fmaxf(tm, __shfl_xor(tm, 16));
        tm = fmaxf(tm, __shfl_xor(tm, 32));
        float mnew = fmaxf(m_run, tm);
        float ts = 0.f;
#pragma unroll
        for (int sm = 0; sm < 4; ++sm)
#pragma unroll
            for (int r = 0; r < 4; ++r) {
                float p = __expf(sf[sm][r] - mnew);
                sf[sm][r] = p;
                ts += p;
            }
        ts += __shfl_xor(ts, 16);
        ts += __shfl_xor(ts, 32);
        float fr = __expf(m_run - mnew);
        l_run = l_run * fr + ts;
        m_run = mnew;
        acc0 *= fr; acc1 *= fr; acc2 *= fr; acc3 *= fr;

#pragma unroll
        for (int sm = 0; sm < 4; ++sm) {
            bf16x4 pb = {(__bf16)sf[sm][0], (__bf16)sf[sm][1], (__bf16)sf[sm][2], (__bf16)sf[sm][3]};
            *(bf16x4*)&pL[w][lo][16 * sm + hi * 4] = pb;
        }
        bf16x8 pf0 = *(const bf16x8*)&pL[w][lo][hi * 8];
        bf16x8 pf1 = *(const bf16x8*)&pL[w][lo][32 + hi * 8];
        acc0 = mfma16(*(const bf16x8*)&vL[lo][hi * 8], pf0, acc0);
        acc1 = mfma16(*(const bf16x8*)&vL[16 + lo][hi * 8], pf0, acc1);
        acc2 = mfma16(*(const bf16x8*)&vL[32 + lo][hi * 8], pf0, acc2);
        acc3 = mfma16(*(const bf16x8*)&vL[48 + lo][hi * 8], pf0, acc3);
        acc0 = mfma16(*(const bf16x8*)&vL[lo][32 + hi * 8], pf1, acc0);
        acc1 = mfma16(*(const bf16x8*)&vL[16 + lo][32 + hi * 8], pf1, acc1);
        acc2 = mfma16(*(const bf16x8*)&vL[32 + lo][32 + hi * 8], pf1, acc2);
        acc3 = mfma16(*(const bf16x8*)&vL[48 + lo][32 + hi * 8], pf1, acc3);
    }

    float rl = vsc / l_run;
    __syncthreads();
    {
        bf16x4 o0 = {(__bf16)(acc0[0] * rl), (__bf16)(acc0[1] * rl), (__bf16)(acc0[2] * rl), (__bf16)(acc0[3] * rl)};
        bf16x4 o1 = {(__bf16)(acc1[0] * rl), (__bf16)(acc1[1] * rl), (__bf16)(acc1[2] * rl), (__bf16)(acc1[3] * rl)};
        bf16x4 o2 = {(__bf16)(acc2[0] * rl), (__bf16)(acc2[1] * rl), (__bf16)(acc2[2] * rl), (__bf16)(acc2[3] * rl)};
        bf16x4 o3 = {(__bf16)(acc3[0] * rl), (__bf16)(acc3[1] * rl), (__bf16)(acc3[2] * rl), (__bf16)(acc3[3] * rl)};
        *(bf16x4*)&qT[16 * w + lo][0  + hi * 4] = o0;
        *(bf16x4*)&qT[16 * w + lo][16 + hi * 4] = o1;
        *(bf16x4*)&qT[16 * w + lo][32 + hi * 4] = o2;
        *(bf16x4*)&qT[16 * w + lo][48 + hi * 4] = o3;
    }
    __syncthreads();
    __bf16* ap = aT + ((size_t)b * 1024 + t0 + (tid >> 2)) * 512 + hh * 64;
    bf16x8 v0 = *(const bf16x8*)&qT[tid >> 2][(tid & 3) * 8];
    bf16x8 v1 = *(const bf16x8*)&qT[tid >> 2][32 + (tid & 3) * 8];
    *(bf16x8*)(ap + (tid & 3) * 8) = v0;
    *(bf16x8*)(ap + 32 + (tid & 3) * 8) = v1;
}

extern "C" void kernel_launch(void* const* d_in, const int* in_sizes, int n_in,
                              void* d_out, int out_size, void* d_ws, size_t ws_size,
                              hipStream_t stream) {
    const float* x      = (const float*)d_in[0];
    const float* gn_w   = (const float*)d_in[1];
    const float* gn_b   = (const float*)d_in[2];
    const float* qkv_w  = (const float*)d_in[3];
    const float* qkv_b  = (const float*)d_in[4];
    const float* proj_w = (const float*)d_in[5];
    const float* proj_b = (const float*)d_in[6];
    char* ws = (char*)d_ws;
    __bf16*   qkv16 = (__bf16*)(ws + QKV_OFF);  // bf16 qkv intermediate
    __bf16*   hT  = (__bf16*)(ws + HT_OFF);     // hT, later reused as aT
    __bf16*   wq  = (__bf16*)(ws + WQ_OFF);
    __bf16*   wp  = (__bf16*)(ws + WP_OFF);
    float*    pmm = (float*)(ws + MM_OFF);      // 3 x 512 x {mn,mx} partials
    float*    gst = (float*)(ws + GST_OFF);     // mean[256], rstd[256]
    __bf16*   ki  = (__bf16*)(ws + KI_OFF);
    __bf16*   vi  = (__bf16*)(ws + VI_OFF);
    float* out = (float*)d_out;

    gnstats<<<1280, 256, 0, stream>>>(x, qkv_w, wq, proj_w, wp, gst);
    gnapply<<<256, 256, 0, stream>>>(x, gn_w, gn_b, gst, hT);
    mgemm6<128, 12, true, false, true><<<768, 256, 0, stream>>>(wq, hT, qkv_b, nullptr, qkv16, 1536, pmm);
    if (ws_size >= NEED_NEW) {
        quant_kv<<<1024, 256, 0, stream>>>(qkv16, pmm, ki, vi);
        attn5<<<512, 512, 0, stream>>>(qkv16, ki, vi, pmm, hT);
    } else {
        attn_mfma<<<1024, 256, 0, stream>>>(qkv16, pmm, hT);
    }
    mgemm6<64, 8, false, true, false><<<512, 256, 0, stream>>>(wp, hT, proj_b, x, out, 512, nullptr);
}

// Round 16
// 86.390 us; speedup vs baseline: 1.1641x; 1.0057x over previous
//
#include <hip/hip_runtime.h>

typedef __attribute__((ext_vector_type(8))) __bf16 bf16x8;
typedef __attribute__((ext_vector_type(4))) __bf16 bf16x4;
typedef __attribute__((ext_vector_type(4))) float  f32x4;

// Problem: x (8,512,32,32) fp32 -> B=8, C=512, T=1024; 32 groups; 8 heads (ch=64)

// ws layout (bytes)
static constexpr size_t QKV_OFF = 0;                     // bf16 (8,1536,1024) 24MB
static constexpr size_t HT_OFF  = 50331648;              // bf16 (8,1024,512) 8MB: hT then aT
static constexpr size_t WQ_OFF  = HT_OFF + 8388608;      // bf16 (1536,512)
static constexpr size_t WP_OFF  = WQ_OFF + 1572864;      // bf16 (512,512)
static constexpr size_t MM_OFF  = WP_OFF + 524288;       // pmm: 3 x 512 slots x {mn,mx} = 12288B
static constexpr size_t GST_OFF = MM_OFF + 12288;        // mean[256], rstd[256] f32
static constexpr size_t KI_OFF  = MM_OFF + 16384;        // bf16 (64,1024,64) 8MB
static constexpr size_t VI_OFF  = KI_OFF + 8388608;      // (reserved)
static constexpr size_t NEED_NEW = VI_OFF + 8388608;

// integer-valued dequant core: clip(rint(x/s)+zp,0,255)-zp == clip(rint(x/s), -zp, 255-zp)
__device__ __forceinline__ float dqi(float x, float inv_s, float zp) {
    float y = rintf(x * inv_s);
    return fminf(fmaxf(y, -zp), 255.0f - zp);
}
__device__ __forceinline__ f32x4 mfma16(bf16x8 a, bf16x8 b, f32x4 c) {
    return __builtin_amdgcn_mfma_f32_16x16x32_bf16(a, b, c, 0, 0, 0);
}
__device__ __forceinline__ float exp2i(float x) {  // raw v_exp_f32 (2^x)
    float r;
    asm("v_exp_f32 %0, %1" : "=v"(r) : "v"(x));
    return r;
}
__device__ __forceinline__ void glds16(const __bf16* g, __bf16* l) {
    __builtin_amdgcn_global_load_lds((const __attribute__((address_space(1))) void*)g,
                                     (__attribute__((address_space(3))) void*)l, 16, 0, 0);
}
template <int N> __device__ __forceinline__ void waitv() {
    asm volatile("s_waitcnt vmcnt(%0)" :: "n"(N) : "memory");
}
__device__ __forceinline__ void bar_raw() {
    asm volatile("s_barrier" ::: "memory");
}

// reduce pmm[id][512][2] partials -> (mn, mx). 256-thread version (2 slots/thread).
__device__ __forceinline__ void red_mm(const float* __restrict__ pmm, int id, int tid,
                                       float* sred, float& mn_out, float& mx_out) {
    const float* p = pmm + id * 1024;
    float mn = fminf(p[tid * 2],     p[(tid + 256) * 2]);
    float mx = fmaxf(p[tid * 2 + 1], p[(tid + 256) * 2 + 1]);
#pragma unroll
    for (int m = 1; m < 64; m <<= 1) {
        mn = fminf(mn, __shfl_xor(mn, m));
        mx = fmaxf(mx, __shfl_xor(mx, m));
    }
    if ((tid & 63) == 0) { sred[(tid >> 6) * 2] = mn; sred[(tid >> 6) * 2 + 1] = mx; }
    __syncthreads();
    mn = fminf(fminf(sred[0], sred[2]), fminf(sred[4], sred[6]));
    mx = fmaxf(fmaxf(sred[1], sred[3]), fmaxf(sred[5], sred[7]));
    __syncthreads();
    mn_out = fminf(mn, 0.0f);
    mx_out = fmaxf(mx, 0.0f);
}

// 512-thread version (1 slot/thread)
__device__ __forceinline__ void red_mm8(const float* __restrict__ pmm, int id, int tid,
                                        float* sred, float& mn_out, float& mx_out) {
    const float* p = pmm + id * 1024;
    float mn = p[tid * 2];
    float mx = p[tid * 2 + 1];
#pragma unroll
    for (int m = 1; m < 64; m <<= 1) {
        mn = fminf(mn, __shfl_xor(mn, m));
        mx = fmaxf(mx, __shfl_xor(mx, m));
    }
    if ((tid & 63) == 0) { sred[(tid >> 6) * 2] = mn; sred[(tid >> 6) * 2 + 1] = mx; }
    __syncthreads();
    float a = fminf(fminf(sred[0], sred[2]), fminf(sred[4], sred[6]));
    float b = fminf(fminf(sred[8], sred[10]), fminf(sred[12], sred[14]));
    mn = fminf(a, b);
    a = fmaxf(fmaxf(sred[1], sred[3]), fmaxf(sred[5], sred[7]));
    b = fmaxf(fmaxf(sred[9], sred[11]), fmaxf(sred[13], sred[15]));
    mx = fmaxf(a, b);
    __syncthreads();
    mn_out = fminf(mn, 0.0f);
    mx_out = fmaxf(mx, 0.0f);
}

// ---------------- gnstats: weight fp32->bf16 convert + per-(b,g) mean/rstd (XCD-aligned) ----------------
__global__ __launch_bounds__(256) void gnstats(const float* __restrict__ x,
                                               const float* __restrict__ qw,
                                               __bf16* __restrict__ wq,
                                               const float* __restrict__ pw,
                                               __bf16* __restrict__ wp,
                                               float* __restrict__ gst) {
    int bid = blockIdx.x, tid = threadIdx.x;
    if (bid < 1024) {
        if (bid < 768) {
            int i = bid * 256 + tid;
            float4 v = ((const float4*)qw)[i];
            bf16x4 o = {(__bf16)v.x, (__bf16)v.y, (__bf16)v.z, (__bf16)v.w};
            ((bf16x4*)wq)[i] = o;
        } else {
            int i = (bid - 768) * 256 + tid;
            float4 v = ((const float4*)pw)[i];
            bf16x4 o = {(__bf16)v.x, (__bf16)v.y, (__bf16)v.z, (__bf16)v.w};
            ((bf16x4*)wp)[i] = o;
        }
        return;
    }
    int blk = bid - 1024;
    int b = blk & 7, g = blk >> 3;   // batch b on XCD b (matches gnapply / proj residual reads)
    const float* xp = x + (size_t)(b * 512 + g * 16) * 1024;

    float sum = 0.f, ss = 0.f;
#pragma unroll
    for (int i = 0; i < 16; ++i) {
        float4 v = *(const float4*)(xp + (size_t)i * 1024 + tid * 4);
        sum += v.x + v.y + v.z + v.w;
        ss  += v.x * v.x + v.y * v.y + v.z * v.z + v.w * v.w;
    }
#pragma unroll
    for (int m = 1; m < 64; m <<= 1) {
        sum += __shfl_xor(sum, m);
        ss  += __shfl_xor(ss, m);
    }
    __shared__ float s1[4], s2[4];
    int wid = tid >> 6;
    if ((tid & 63) == 0) { s1[wid] = sum; s2[wid] = ss; }
    __syncthreads();
    if (tid == 0) {
        sum = s1[0] + s1[1] + s1[2] + s1[3];
        ss  = s2[0] + s2[1] + s2[2] + s2[3];
        float mean = sum * (1.0f / 16384.0f);
        float var  = ss * (1.0f / 16384.0f) - mean * mean;
        int idx = b * 32 + g;
        gst[idx]       = mean;
        gst[256 + idx] = rsqrtf(var + 1e-5f);
    }
}

// ---------------- gnapply: t-major normalize + transpose, coalesced both sides ----------------
__global__ __launch_bounds__(256) void gnapply(const float* __restrict__ x,
                                               const float* __restrict__ w,
                                               const float* __restrict__ bv,
                                               const float* __restrict__ gst,
                                               __bf16* __restrict__ hT) {
    int f = blockIdx.x;
    int b = f & 7, ts = f >> 3;
    int t0 = ts * 32;
    int tid = threadIdx.x;

    __shared__ __bf16 sH[32][520];
    int cl = tid >> 3;
    int tl = (tid & 7) * 4;

#pragma unroll
    for (int ci = 0; ci < 16; ++ci) {
        int c = ci * 32 + cl;
        int g = c >> 4;
        float mean = gst[b * 32 + g];
        float rstd = gst[256 + b * 32 + g];
        float wc = w[c] * rstd, bc = bv[c];
        float4 v = *(const float4*)(x + ((size_t)(b * 512 + c)) * 1024 + t0 + tl);
        sH[tl + 0][c] = (__bf16)((v.x - mean) * wc + bc);
        sH[tl + 1][c] = (__bf16)((v.y - mean) * wc + bc);
        sH[tl + 2][c] = (__bf16)((v.z - mean) * wc + bc);
        sH[tl + 3][c] = (__bf16)((v.w - mean) * wc + bc);
    }
    __syncthreads();
    int lane = tid & 63, wv = tid >> 6;
#pragma unroll
    for (int it = 0; it < 8; ++it) {
        int row = it * 4 + wv;
        bf16x8 o = *(const bf16x8*)&sH[row][lane * 8];
        *(bf16x8*)(hT + ((size_t)(b * 1024 + t0 + row)) * 512 + lane * 8) = o;
    }
}

// ---------------- MFMA GEMM v6: BK=64 swizzle + counted-vmcnt dbuf; per-64-row minmax; bf16 out opt ----------------
template <int MTILE, int MOT, bool MINMAX, bool RESID, bool OUT16>
__global__ __launch_bounds__(256, 2) void mgemm6(const __bf16* __restrict__ A,   // [M][512]
                                                 const __bf16* __restrict__ Bt,  // [8][1024][512]
                                                 const float* __restrict__ bias,
                                                 const float* __restrict__ resid,
                                                 void* __restrict__ outv,
                                                 int M, float* __restrict__ pmm) {
    constexpr int NF  = (MTILE == 128) ? 4 : 2;
    constexpr int ASZ = MTILE * 64;
    constexpr int BSZ = 128 * 64;
    constexpr int LA  = MTILE / 32;
    constexpr int L   = LA + 4;
    constexpr int STG = 2 * (ASZ + BSZ) * 2;
    constexpr int CSB = 64 * 132 * 4;
    __shared__ __attribute__((aligned(16))) char smem_raw[(STG > CSB) ? STG : CSB];
    __bf16* sA0 = (__bf16*)smem_raw;
    __bf16* sA1 = sA0 + ASZ;
    __bf16* sB0 = sA1 + ASZ;
    __bf16* sB1 = sB0 + BSZ;
    __shared__ float smn[4], smx[4];

    int tid = threadIdx.x;
    int l = tid & 63, w = tid >> 6;
    int lo = l & 15, hi = l >> 4;

    int f = blockIdx.x;
    constexpr int NWG = MOT * 64;
    int wg = (f & 7) * (NWG / 8) + (f >> 3);
    int mo = wg % MOT, nb = wg / MOT;
    int nt = nb & 7, b = nb >> 3;

    const __bf16* Ap = A + (size_t)mo * MTILE * 512;
    const __bf16* Bp = Bt + ((size_t)b * 1024 + (size_t)nt * 128) * 512;
    int m0 = (MTILE == 128) ? (w >> 1) * 64 : 0;
    int n0 = (MTILE == 128) ? (w & 1) * 64 : w * 32;
    f32x4 acc[4][NF] = {};
    int scd = tid & 7;

    auto STAGE = [&](__bf16* dA, __bf16* dB, int k0) {
#pragma unroll
        for (int p = 0; p < LA; ++p) {
            int lin = p * 2048 + tid * 8;
            int row = lin >> 6;
            glds16(Ap + (size_t)row * 512 + k0 + ((scd ^ (row & 7)) << 3), dA + lin);
        }
#pragma unroll
        for (int p = 0; p < 4; ++p) {
            int lin = p * 2048 + tid * 8;
            int row = lin >> 6;
            glds16(Bp + (size_t)row * 512 + k0 + ((scd ^ (row & 7)) << 3), dB + lin);
        }
    };
    auto COMPUTE = [&](const __bf16* cA, const __bf16* cB) {
#pragma unroll
        for (int kk = 0; kk < 2; ++kk) {
            int rch = ((kk * 4 + hi) ^ (lo & 7)) << 3;
            bf16x8 af[4], bfr[NF];
#pragma unroll
            for (int i = 0; i < 4; ++i) af[i] = *(const bf16x8*)&cA[(m0 + 16 * i + lo) * 64 + rch];
#pragma unroll
            for (int j = 0; j < NF; ++j) bfr[j] = *(const bf16x8*)&cB[(n0 + 16 * j + lo) * 64 + rch];
#pragma unroll
            for (int i = 0; i < 4; ++i)
#pragma unroll
                for (int j = 0; j < NF; ++j) acc[i][j] = mfma16(af[i], bfr[j], acc[i][j]);
        }
    };

    STAGE(sA0, sB0, 0);
#pragma unroll
    for (int kp = 0; kp < 8; kp += 2) {
        if (kp + 1 < 8) { STAGE(sA1, sB1, (kp + 1) * 64); waitv<L>(); } else { waitv<0>(); }
        bar_raw();
        COMPUTE(sA0, sB0);
        bar_raw();
        if (kp + 2 < 8) { STAGE(sA0, sB0, (kp + 2) * 64); waitv<L>(); } else { waitv<0>(); }
        bar_raw();
        COMPUTE(sA1, sB1);
        bar_raw();
    }

    float* cs = (float*)smem_raw;
    constexpr int NH = (MTILE == 128) ? 2 : 1;
#pragma unroll
    for (int h = 0; h < NH; ++h) {
        float mn = 1e30f, mx = -1e30f;
        __syncthreads();
        if (MTILE == 64 || (w >> 1) == h) {
#pragma unroll
            for (int i = 0; i < 4; ++i)
#pragma unroll
                for (int r = 0; r < 4; ++r) {
                    int rl = 16 * i + hi * 4 + r;
                    float bi = bias[mo * MTILE + h * 64 + rl];
#pragma unroll
                    for (int j = 0; j < NF; ++j)
                        cs[rl * 132 + n0 + 16 * j + lo] = acc[i][j][r] + bi;
                }
        }
        __syncthreads();
#pragma unroll
        for (int it = 0; it < 8; ++it) {
            int lin = it * 256 + tid;
            int rr = lin >> 5, cc = (lin & 31) << 2;
            float4 v = *(const float4*)&cs[rr * 132 + cc];
            if (MINMAX) {
                mn = fminf(mn, fminf(fminf(v.x, v.y), fminf(v.z, v.w)));
                mx = fmaxf(mx, fmaxf(fmaxf(v.x, v.y), fmaxf(v.z, v.w)));
            }
            int grow = mo * MTILE + h * 64 + rr;
            size_t gaddr = ((size_t)b * M + grow) * 1024 + nt * 128 + cc;
            if (RESID) {
                float4 rv = *(const float4*)&resid[gaddr];
                v.x += rv.x; v.y += rv.y; v.z += rv.z; v.w += rv.w;
            }
            if (OUT16) {
                bf16x4 o16 = {(__bf16)v.x, (__bf16)v.y, (__bf16)v.z, (__bf16)v.w};
                *(bf16x4*)&(((__bf16*)outv)[gaddr]) = o16;
            } else {
                *(float4*)&(((float*)outv)[gaddr]) = v;
            }
        }

        if (MINMAX) {
            // per-64-row-half reduction: this half belongs to tensor id=(2mo+h)%3, head (2mo+h)/3
#pragma unroll
            for (int msk = 1; msk < 64; msk <<= 1) {
                mn = fminf(mn, __shfl_xor(mn, msk));
                mx = fmaxf(mx, __shfl_xor(mx, msk));
            }
            if (l == 0) { smn[w] = mn; smx[w] = mx; }
            __syncthreads();
            if (tid == 0) {
                mn = fminf(fminf(smn[0], smn[1]), fminf(smn[2], smn[3]));
                mx = fmaxf(fmaxf(smx[0], smx[1]), fmaxf(smx[2], smx[3]));
                int o = 2 * mo + h;
                int id = o % 3;                     // q/k/v per the head-interleaved layout
                int slot = (o / 3) * 64 + nb;       // 0..511, unique per (id, block-half)
                pmm[id * 1024 + slot * 2]     = mn;
                pmm[id * 1024 + slot * 2 + 1] = mx;
            }
            __syncthreads();   // smn/smx reuse guard for next half
        }
    }
}

// ---------------- quant K pass (V now dequantized inline in attn), XCD-aligned ----------------
__global__ __launch_bounds__(256) void quant_k(const __bf16* __restrict__ qkv,
                                               const float* __restrict__ pmm,
                                               __bf16* __restrict__ ki) {
    int f = blockIdx.x;
    int b = f & 7;
    int r2 = f >> 3;
    int hh = r2 & 7, tt = r2 >> 3;
    int bh = b * 8 + hh;
    int t0 = tt * 64;
    const __bf16* kg = qkv + ((size_t)(b * 1536 + hh * 192) + 64) * 1024;
    int tid = threadIdx.x;

    __shared__ float sred[8];
    float mn1, mx1;
    red_mm(pmm, 1, tid, sred, mn1, mx1);
    float ksc = fmaxf((mx1 - mn1) * (1.f / 255.f), 1e-8f), kzp = rintf(-mn1 / ksc);
    float inv_k = 1.f / ksc;

    __shared__ __bf16 sT[64][68];
    int cr = tid >> 4, t4 = tid & 15;
    int s = tid >> 2, c0 = (tid & 3) * 16;

#pragma unroll
    for (int r = 0; r < 4; ++r) {
        int c = 16 * r + cr;
        bf16x4 v = *(const bf16x4*)(kg + (size_t)c * 1024 + t0 + t4 * 4);
        sT[t4 * 4 + 0][c] = (__bf16)dqi((float)v[0], inv_k, kzp);
        sT[t4 * 4 + 1][c] = (__bf16)dqi((float)v[1], inv_k, kzp);
        sT[t4 * 4 + 2][c] = (__bf16)dqi((float)v[2], inv_k, kzp);
        sT[t4 * 4 + 3][c] = (__bf16)dqi((float)v[3], inv_k, kzp);
    }
    __syncthreads();
    bf16x8 a0 = *(const bf16x8*)&sT[s][c0];
    bf16x8 a1 = *(const bf16x8*)&sT[s][c0 + 8];
    __bf16* kd = ki + ((size_t)bh * 1024 + t0 + s) * 64 + c0;
    *(bf16x8*)kd = a0;
    *(bf16x8*)(kd + 8) = a1;
}

// ---------------- attention: QBLK=128, 8 waves, dbuf K/V, 1 barrier/tile; V dequant inline ----------------
__global__ __launch_bounds__(512, 4) void attn5(const __bf16* __restrict__ qkv,
                                                const __bf16* __restrict__ ki,
                                                const float* __restrict__ pmm,
                                                __bf16* __restrict__ aT) {
    int f = blockIdx.x;
    int bh = (f & 7) * 8 + ((f >> 3) & 7);  // batch b = f&7 -> XCD b
    int tt = f >> 6;                        // 0..7
    int b = bh >> 3, hh = bh & 7;
    int t0 = tt * 128;
    const __bf16* qg = qkv + (size_t)(b * 1536 + hh * 192) * 1024;
    const __bf16* kb = ki + (size_t)bh * 65536;
    const __bf16* vb = qg + (size_t)128 * 1024;   // V straight from qkv16 (same layout as old vi)
    int tid = threadIdx.x;

    __shared__ float sred[16];
    float mn0, mx0, mn1, mx1, mn2, mx2;
    red_mm8(pmm, 0, tid, sred, mn0, mx0);
    red_mm8(pmm, 1, tid, sred, mn1, mx1);
    red_mm8(pmm, 2, tid, sred, mn2, mx2);
    float qsc = fmaxf((mx0 - mn0) * (1.f / 255.f), 1e-8f), qzp = rintf(-mn0 / qsc);
    float ksc = fmaxf((mx1 - mn1) * (1.f / 255.f), 1e-8f);
    float vsc = fmaxf((mx2 - mn2) * (1.f / 255.f), 1e-8f), vzp = rintf(-mn2 / vsc);
    float inv_q = 1.f / qsc, inv_v = 1.f / vsc;
    float alpha2 = qsc * ksc * 0.125f * 1.4426950408889634f;  // alpha * log2(e)
    float thr = 11.5415603f / alpha2;                          // 8 nats in raw-score units

    __shared__ __bf16 sh[128][72];   // q stage -> per-wave P -> output stage
    __shared__ __bf16 kS[2][4096];   // K tile (s,c), chunk-swizzled, double-buffered
    __shared__ __bf16 vS[2][4096];   // V tile (c,s), chunk-swizzled, double-buffered
    int l = tid & 63, w = tid >> 6;
    int lo = l & 15, hi = l >> 4;

    // staging geometry: thread -> row (0..63), one 16B chunk each for K and V
    int srow = tid >> 3, sc = tid & 7;
    int swz = (sc ^ (srow & 7)) << 3;
    const __bf16* kROW = kb + (size_t)srow * 64;          // + st*4096
    const __bf16* vROW = vb + (size_t)srow * 1024;        // + st*64
    int lx = lo & 7;
    int rc0 = (hi ^ lx) << 3;
    int rc1 = ((4 + hi) ^ lx) << 3;

    // issue tile-0 loads early; hide under q staging
    bf16x8 kr = *(const bf16x8*)(kROW + sc * 8);
    bf16x8 vr = *(const bf16x8*)(vROW + sc * 8);

    // inline q stage: transpose + dequant to integer-valued bf16 (128 t x 64 c)
    {
        int c0 = (tid >> 5) * 4;     // 0..60
        int tl = tid & 31;
#pragma unroll
        for (int r = 0; r < 4; ++r) {
            int t = tl + 32 * r;
            float y0 = dqi((float)qg[(size_t)(c0 + 0) * 1024 + t0 + t], inv_q, qzp);
            float y1 = dqi((float)qg[(size_t)(c0 + 1) * 1024 + t0 + t], inv_q, qzp);
            float y2 = dqi((float)qg[(size_t)(c0 + 2) * 1024 + t0 + t], inv_q, qzp);
            float y3 = dqi((float)qg[(size_t)(c0 + 3) * 1024 + t0 + t], inv_q, qzp);
            bf16x4 o = {(__bf16)y0, (__bf16)y1, (__bf16)y2, (__bf16)y3};
            *(bf16x4*)&sh[t][c0] = o;
        }
    }
    __syncthreads();
    bf16x8 qf0 = *(const bf16x8*)&sh[16 * w + lo][hi * 8];
    bf16x8 qf1 = *(const bf16x8*)&sh[16 * w + lo][32 + hi * 8];
    // stage tile 0 (waits vmcnt via data dep); V dequantized to integer-values at write
    {
        bf16x8 vq;
#pragma unroll
        for (int j = 0; j < 8; ++j) vq[j] = (__bf16)dqi((float)vr[j], inv_v, vzp);
        *(bf16x8*)(kS[0] + srow * 64 + swz) = kr;
        *(bf16x8*)(vS[0] + srow * 64 + swz) = vq;
    }
    __syncthreads();   // q reads done + tile 0 staged

    f32x4 acc0 = {}, acc1 = {}, acc2 = {}, acc3 = {};
    float m_run = -1e30f, l_run = 0.f;

    for (int st = 0; st < 16; ++st) {
        const __bf16* kc = kS[st & 1];
        const __bf16* vc = vS[st & 1];
        if (st < 15) {   // T14: issue next-tile loads before compute
            kr = *(const bf16x8*)(kROW + (st + 1) * 4096 + sc * 8);
            vr = *(const bf16x8*)(vROW + (st + 1) * 64 + sc * 8);
        }

        // scores: D[s][t] = K·Q (raw integer dot products)
        f32x4 sf[4] = {};
        __builtin_amdgcn_s_setprio(1);
#pragma unroll
        for (int sm = 0; sm < 4; ++sm)
            sf[sm] = mfma16(*(const bf16x8*)(kc + (16 * sm + lo) * 64 + rc0), qf0, sf[sm]);
#pragma unroll
        for (int sm = 0; sm < 4; ++sm)
            sf[sm] = mfma16(*(const bf16x8*)(kc + (16 * sm + lo) * 64 + rc1), qf1, sf[sm]);
        __builtin_amdgcn_s_setprio(0);

        // online softmax in exp2 space (t = lane-local)
        float tm = -1e30f;
#pragma unroll
        for (int sm = 0; sm < 4; ++sm) {
            float a = fmaxf(sf[sm][0], sf[sm][1]);
            float c = fmaxf(sf[sm][2], sf[sm][3]);
            tm = fmaxf(tm, fmaxf(a, c));
        }
        tm = fmaxf(tm, __shfl_xor(tm, 16));
        tm = fmaxf(tm, __shfl_xor(tm, 32));
        if (!__all(tm <= m_run + thr)) {   // defer-max
            float mnew = fmaxf(m_run, tm);
            float fr = exp2i(alpha2 * (m_run - mnew));
            acc0 *= fr; acc1 *= fr; acc2 *= fr; acc3 *= fr;
            l_run *= fr;
            m_run = mnew;
        }
        float cc = -alpha2 * m_run;
        float ts = 0.f;
#pragma unroll
        for (int sm = 0; sm < 4; ++sm)
#pragma unroll
            for (int r = 0; r < 4; ++r) {
                float p = exp2i(fmaf(sf[sm][r], alpha2, cc));
                sf[sm][r] = p;
                ts += p;
            }
        ts += __shfl_xor(ts, 16);
        ts += __shfl_xor(ts, 32);
        l_run += ts;

        // P -> LDS (wave-private rows)
#pragma unroll
        for (int sm = 0; sm < 4; ++sm) {
            bf16x4 pb = {(__bf16)sf[sm][0], (__bf16)sf[sm][1], (__bf16)sf[sm][2], (__bf16)sf[sm][3]};
            *(bf16x4*)&sh[16 * w + lo][16 * sm + hi * 4] = pb;
        }
        bf16x8 pf0 = *(const bf16x8*)&sh[16 * w + lo][hi * 8];
        bf16x8 pf1 = *(const bf16x8*)&sh[16 * w + lo][32 + hi * 8];

        // PV: D[c][t] += V·P
        __builtin_amdgcn_s_setprio(1);
        acc0 = mfma16(*(const bf16x8*)(vc + (lo) * 64 + rc0), pf0, acc0);
        acc1 = mfma16(*(const bf16x8*)(vc + (16 + lo) * 64 + rc0), pf0, acc1);
        acc2 = mfma16(*(const bf16x8*)(vc + (32 + lo) * 64 + rc0), pf0, acc2);
        acc3 = mfma16(*(const bf16x8*)(vc + (48 + lo) * 64 + rc0), pf0, acc3);
        acc0 = mfma16(*(const bf16x8*)(vc + (lo) * 64 + rc1), pf1, acc0);
        acc1 = mfma16(*(const bf16x8*)(vc + (16 + lo) * 64 + rc1), pf1, acc1);
        acc2 = mfma16(*(const bf16x8*)(vc + (32 + lo) * 64 + rc1), pf1, acc2);
        acc3 = mfma16(*(const bf16x8*)(vc + (48 + lo) * 64 + rc1), pf1, acc3);
        __builtin_amdgcn_s_setprio(0);

        if (st < 15) {   // write-late into the other buffer (readers finished at prev barrier)
            bf16x8 vq;
#pragma unroll
            for (int j = 0; j < 8; ++j) vq[j] = (__bf16)dqi((float)vr[j], inv_v, vzp);
            *(bf16x8*)(kS[(st + 1) & 1] + srow * 64 + swz) = kr;
            *(bf16x8*)(vS[(st + 1) & 1] + srow * 64 + swz) = vq;
        }
        __syncthreads();   // single barrier per tile
    }

    float rl = vsc / l_run;
    {
        bf16x4 o0 = {(__bf16)(acc0[0] * rl), (__bf16)(acc0[1] * rl), (__bf16)(acc0[2] * rl), (__bf16)(acc0[3] * rl)};
        bf16x4 o1 = {(__bf16)(acc1[0] * rl), (__bf16)(acc1[1] * rl), (__bf16)(acc1[2] * rl), (__bf16)(acc1[3] * rl)};
        bf16x4 o2 = {(__bf16)(acc2[0] * rl), (__bf16)(acc2[1] * rl), (__bf16)(acc2[2] * rl), (__bf16)(acc2[3] * rl)};
        bf16x4 o3 = {(__bf16)(acc3[0] * rl), (__bf16)(acc3[1] * rl), (__bf16)(acc3[2] * rl), (__bf16)(acc3[3] * rl)};
        *(bf16x4*)&sh[16 * w + lo][0  + hi * 4] = o0;
        *(bf16x4*)&sh[16 * w + lo][16 + hi * 4] = o1;
        *(bf16x4*)&sh[16 * w + lo][32 + hi * 4] = o2;
        *(bf16x4*)&sh[16 * w + lo][48 + hi * 4] = o3;
    }
    __syncthreads();
    __bf16* ap = aT + ((size_t)b * 1024 + t0 + (tid >> 2)) * 512 + hh * 64;
    bf16x8 v0 = *(const bf16x8*)&sh[tid >> 2][(tid & 3) * 8];
    bf16x8 v1 = *(const bf16x8*)&sh[tid >> 2][32 + (tid & 3) * 8];
    *(bf16x8*)(ap + (tid & 3) * 8) = v0;
    *(bf16x8*)(ap + 32 + (tid & 3) * 8) = v1;
}

// ---------------- fallback attention (bf16 qkv, used if ws too small) ----------------
__global__ __launch_bounds__(256) void attn_mfma(const __bf16* __restrict__ qkv,
                                                 const float* __restrict__ pmm,
                                                 __bf16* __restrict__ aT) {
    int f = blockIdx.x;
    int bh = (f & 7) * 8 + ((f >> 3) & 7);
    int tt = f >> 6;
    int b = bh >> 3, hh = bh & 7;
    int t0 = tt * 64;
    const __bf16* qg = qkv + (size_t)(b * 1536 + hh * 192) * 1024;
    const __bf16* kg = qg + (size_t)64 * 1024;
    const __bf16* vg = qg + (size_t)128 * 1024;
    int tid = threadIdx.x;

    __shared__ float sred[8];
    float mn0, mx0, mn1, mx1, mn2, mx2;
    red_mm(pmm, 0, tid, sred, mn0, mx0);
    red_mm(pmm, 1, tid, sred, mn1, mx1);
    red_mm(pmm, 2, tid, sred, mn2, mx2);
    float qsc = fmaxf((mx0 - mn0) * (1.f / 255.f), 1e-8f), qzp = rintf(-mn0 / qsc);
    float ksc = fmaxf((mx1 - mn1) * (1.f / 255.f), 1e-8f), kzp = rintf(-mn1 / ksc);
    float vsc = fmaxf((mx2 - mn2) * (1.f / 255.f), 1e-8f), vzp = rintf(-mn2 / vsc);
    float inv_q = 1.f / qsc, inv_k = 1.f / ksc, inv_v = 1.f / vsc;
    float alpha = qsc * ksc * 0.125f;

    __shared__ __bf16 qT[64][72];
    __shared__ __bf16 kT[64][72];
    __shared__ __bf16 vL[64][72];
    __shared__ __bf16 pL[4][16][72];

    int l = tid & 63, w = tid >> 6;
    int lo = l & 15, hi = l >> 4;
    int c0 = (tid >> 4) * 4;
    int tl = tid & 15;

#pragma unroll
    for (int r = 0; r < 4; ++r) {
        int t = tl + 16 * r;
        float y0 = dqi((float)qg[(size_t)(c0 + 0) * 1024 + t0 + t], inv_q, qzp);
        float y1 = dqi((float)qg[(size_t)(c0 + 1) * 1024 + t0 + t], inv_q, qzp);
        float y2 = dqi((float)qg[(size_t)(c0 + 2) * 1024 + t0 + t], inv_q, qzp);
        float y3 = dqi((float)qg[(size_t)(c0 + 3) * 1024 + t0 + t], inv_q, qzp);
        bf16x4 o = {(__bf16)y0, (__bf16)y1, (__bf16)y2, (__bf16)y3};
        *(bf16x4*)&qT[t][c0] = o;
    }
    __syncthreads();
    bf16x8 qf0 = *(const bf16x8*)&qT[16 * w + lo][hi * 8];
    bf16x8 qf1 = *(const bf16x8*)&qT[16 * w + lo][32 + hi * 8];

    f32x4 acc0 = {}, acc1 = {}, acc2 = {}, acc3 = {};
    float m_run = -1e30f, l_run = 0.f;

    for (int st = 0; st < 16; ++st) {
        int s0 = st * 64;
        __syncthreads();
#pragma unroll
        for (int r = 0; r < 4; ++r) {
            int srow = tl + 16 * r;
            float y0 = dqi((float)kg[(size_t)(c0 + 0) * 1024 + s0 + srow], inv_k, kzp);
            float y1 = dqi((float)kg[(size_t)(c0 + 1) * 1024 + s0 + srow], inv_k, kzp);
            float y2 = dqi((float)kg[(size_t)(c0 + 2) * 1024 + s0 + srow], inv_k, kzp);
            float y3 = dqi((float)kg[(size_t)(c0 + 3) * 1024 + s0 + srow], inv_k, kzp);
            bf16x4 ok = {(__bf16)y0, (__bf16)y1, (__bf16)y2, (__bf16)y3};
            *(bf16x4*)&kT[srow][c0] = ok;
            int c = (tid >> 4) + 16 * r;
            bf16x4 vv = *(const bf16x4*)(vg + (size_t)c * 1024 + s0 + (tid & 15) * 4);
            bf16x4 ov = {(__bf16)dqi((float)vv[0], inv_v, vzp), (__bf16)dqi((float)vv[1], inv_v, vzp),
                         (__bf16)dqi((float)vv[2], inv_v, vzp), (__bf16)dqi((float)vv[3], inv_v, vzp)};
            *(bf16x4*)&vL[c][(tid & 15) * 4] = ov;
        }
        __syncthreads();

        f32x4 sf[4] = {};
#pragma unroll
        for (int sm = 0; sm < 4; ++sm)
            sf[sm] = mfma16(*(const bf16x8*)&kT[16 * sm + lo][hi * 8], qf0, sf[sm]);
#pragma unroll
        for (int sm = 0; sm < 4; ++sm)
            sf[sm] = mfma16(*(const bf16x8*)&kT[16 * sm + lo][32 + hi * 8], qf1, sf[sm]);

        float tm = -1e30f;
#pragma unroll
        for (int sm = 0; sm < 4; ++sm)
#pragma unroll
            for (int r = 0; r < 4; ++r) { sf[sm][r] *= alpha; tm = fmaxf(tm, sf[sm][r]); }
        tm = fmaxf(tm, __shfl_xor(tm, 16));
        tm = fmaxf(tm, __shfl_xor(tm, 32));
        float mnew = fmaxf(m_run, tm);
        float ts = 0.f;
#pragma unroll
        for (int sm = 0; sm < 4; ++sm)
#pragma unroll
            for (int r = 0; r < 4; ++r) {
                float p = __expf(sf[sm][r] - mnew);
                sf[sm][r] = p;
                ts += p;
            }
        ts += __shfl_xor(ts, 16);
        ts += __shfl_xor(ts, 32);
        float fr = __expf(m_run - mnew);
        l_run = l_run * fr + ts;
        m_run = mnew;
        acc0 *= fr; acc1 *= fr; acc2 *= fr; acc3 *= fr;

#pragma unroll
        for (int sm = 0; sm < 4; ++sm) {
            bf16x4 pb = {(__bf16)sf[sm][0], (__bf16)sf[sm][1], (__bf16)sf[sm][2], (__bf16)sf[sm][3]};
            *(bf16x4*)&pL[w][lo][16 * sm + hi * 4] = pb;
        }
        bf16x8 pf0 = *(const bf16x8*)&pL[w][lo][hi * 8];
        bf16x8 pf1 = *(const bf16x8*)&pL[w][lo][32 + hi * 8];
        acc0 = mfma16(*(const bf16x8*)&vL[lo][hi * 8], pf0, acc0);
        acc1 = mfma16(*(const bf16x8*)&vL[16 + lo][hi * 8], pf0, acc1);
        acc2 = mfma16(*(const bf16x8*)&vL[32 + lo][hi * 8], pf0, acc2);
        acc3 = mfma16(*(const bf16x8*)&vL[48 + lo][hi * 8], pf0, acc3);
        acc0 = mfma16(*(const bf16x8*)&vL[lo][32 + hi * 8], pf1, acc0);
        acc1 = mfma16(*(const bf16x8*)&vL[16 + lo][32 + hi * 8], pf1, acc1);
        acc2 = mfma16(*(const bf16x8*)&vL[32 + lo][32 + hi * 8], pf1, acc2);
        acc3 = mfma16(*(const bf16x8*)&vL[48 + lo][32 + hi * 8], pf1, acc3);
    }

    float rl = vsc / l_run;
    __syncthreads();
    {
        bf16x4 o0 = {(__bf16)(acc0[0] * rl), (__bf16)(acc0[1] * rl), (__bf16)(acc0[2] * rl), (__bf16)(acc0[3] * rl)};
        bf16x4 o1 = {(__bf16)(acc1[0] * rl), (__bf16)(acc1[1] * rl), (__bf16)(acc1[2] * rl), (__bf16)(acc1[3] * rl)};
        bf16x4 o2 = {(__bf16)(acc2[0] * rl), (__bf16)(acc2[1] * rl), (__bf16)(acc2[2] * rl), (__bf16)(acc2[3] * rl)};
        bf16x4 o3 = {(__bf16)(acc3[0] * rl), (__bf16)(acc3[1] * rl), (__bf16)(acc3[2] * rl), (__bf16)(acc3[3] * rl)};
        *(bf16x4*)&qT[16 * w + lo][0  + hi * 4] = o0;
        *(bf16x4*)&qT[16 * w + lo][16 + hi * 4] = o1;
        *(bf16x4*)&qT[16 * w + lo][32 + hi * 4] = o2;
        *(bf16x4*)&qT[16 * w + lo][48 + hi * 4] = o3;
    }
    __syncthreads();
    __bf16* ap = aT + ((size_t)b * 1024 + t0 + (tid >> 2)) * 512 + hh * 64;
    bf16x8 v0 = *(const bf16x8*)&qT[tid >> 2][(tid & 3) * 8];
    bf16x8 v1 = *(const bf16x8*)&qT[tid >> 2][32 + (tid & 3) * 8];
    *(bf16x8*)(ap + (tid & 3) * 8) = v0;
    *(bf16x8*)(ap + 32 + (tid & 3) * 8) = v1;
}

extern "C" void kernel_launch(void* const* d_in, const int* in_sizes, int n_in,
                              void* d_out, int out_size, void* d_ws, size_t ws_size,
                              hipStream_t stream) {
    const float* x      = (const float*)d_in[0];
    const float* gn_w   = (const float*)d_in[1];
    const float* gn_b   = (const float*)d_in[2];
    const float* qkv_w  = (const float*)d_in[3];
    const float* qkv_b  = (const float*)d_in[4];
    const float* proj_w = (const float*)d_in[5];
    const float* proj_b = (const float*)d_in[6];
    char* ws = (char*)d_ws;
    __bf16*   qkv16 = (__bf16*)(ws + QKV_OFF);  // bf16 qkv intermediate
    __bf16*   hT  = (__bf16*)(ws + HT_OFF);     // hT, later reused as aT
    __bf16*   wq  = (__bf16*)(ws + WQ_OFF);
    __bf16*   wp  = (__bf16*)(ws + WP_OFF);
    float*    pmm = (float*)(ws + MM_OFF);      // 3 x 512 x {mn,mx} partials
    float*    gst = (float*)(ws + GST_OFF);     // mean[256], rstd[256]
    __bf16*   ki  = (__bf16*)(ws + KI_OFF);
    float* out = (float*)d_out;

    gnstats<<<1280, 256, 0, stream>>>(x, qkv_w, wq, proj_w, wp, gst);
    gnapply<<<256, 256, 0, stream>>>(x, gn_w, gn_b, gst, hT);
    mgemm6<128, 12, true, false, true><<<768, 256, 0, stream>>>(wq, hT, qkv_b, nullptr, qkv16, 1536, pmm);
    if (ws_size >= NEED_NEW) {
        quant_k<<<1024, 256, 0, stream>>>(qkv16, pmm, ki);
        attn5<<<512, 512, 0, stream>>>(qkv16, ki, pmm, hT);
    } else {
        attn_mfma<<<1024, 256, 0, stream>>>(qkv16, pmm, hT);
    }
    mgemm6<64, 8, false, true, false><<<512, 256, 0, stream>>>(wp, hT, proj_b, x, out, 512, nullptr);
}